// Round 2
// baseline (977.447 us; speedup 1.0000x reference)
//
#include <hip/hip_runtime.h>
#include <math.h>

#define EPSF 1e-12f
// N=32, H=W=32 (HW=1024), D=512, K=64, OUT=4096, KD=32768

// ---- kernel 1: s = softmax(x @ W1 + b1); ap = per-block column sums of s ----
// grid 512 x 256 (4 waves). Block owns 64 pixels (lane=pixel); wave h owns
// k-range [h*16, h*16+16). W1/b1 at wave-uniform addresses (scalar loads).
__global__ __launch_bounds__(256) void k_assign(
    const float* __restrict__ x, const float* __restrict__ w1,
    const float* __restrict__ b1, float* __restrict__ s,
    float* __restrict__ ap)
{
    const int lane  = threadIdx.x & 63;
    const int h     = threadIdx.x >> 6;      // 0..3
    const int pix   = blockIdx.x * 64 + lane;
    const int kbase = h * 16;

    float acc[16];
#pragma unroll
    for (int i = 0; i < 16; ++i) acc[i] = b1[kbase + i];

    const float* xrow = x + (size_t)pix * 512;
    for (int dd = 0; dd < 512; dd += 4) {
        float4 xv = *(const float4*)(xrow + dd);
        const float* wr = w1 + (size_t)dd * 64 + kbase;   // uniform
#pragma unroll
        for (int j = 0; j < 4; ++j) {
            const float xs = (j == 0) ? xv.x : (j == 1) ? xv.y : (j == 2) ? xv.z : xv.w;
#pragma unroll
            for (int kk = 0; kk < 16; ++kk)
                acc[kk] = fmaf(xs, wr[(size_t)j * 64 + kk], acc[kk]);
        }
    }

    __shared__ float redm[4][64];
    __shared__ float reds[4][64];
    float m = acc[0];
#pragma unroll
    for (int i = 1; i < 16; ++i) m = fmaxf(m, acc[i]);
    redm[h][lane] = m;
    __syncthreads();
    m = fmaxf(fmaxf(redm[0][lane], redm[1][lane]),
              fmaxf(redm[2][lane], redm[3][lane]));
    float sum = 0.f;
#pragma unroll
    for (int i = 0; i < 16; ++i) { acc[i] = __expf(acc[i] - m); sum += acc[i]; }
    reds[h][lane] = sum;
    __syncthreads();
    const float inv = 1.0f / (reds[0][lane] + reds[1][lane] +
                              reds[2][lane] + reds[3][lane]);
#pragma unroll
    for (int i = 0; i < 16; ++i) acc[i] *= inv;

    float* srow = s + (size_t)pix * 64 + kbase;
#pragma unroll
    for (int i = 0; i < 16; i += 4)
        *(float4*)(srow + i) = make_float4(acc[i], acc[i+1], acc[i+2], acc[i+3]);

    // per-block partial column-sum of s (64 pixels) -> ap[block][64]
#pragma unroll
    for (int i = 0; i < 16; ++i) {
        float v = acc[i];
#pragma unroll
        for (int off = 32; off > 0; off >>= 1) v += __shfl_xor(v, off, 64);
        if (lane == 0) ap[(size_t)blockIdx.x * 64 + kbase + i] = v;
    }
}

// ---- kernel 2: v[n,k,d] = sum_p s[p,k] * x[p,d] (direct, no partials) ----
// grid 256 = n(32) x kh(2) x dc(4); 512 threads (8 waves). Thread owns
// 2 k x 4 d; all 1024 pixels looped. No LDS: s/x rows broadcast via L1/L2.
__global__ __launch_bounds__(512) void k_vlad(
    const float* __restrict__ s, const float* __restrict__ x,
    float* __restrict__ v)
{
    const int b  = blockIdx.x;
    const int n  = b >> 3;
    const int kh = (b >> 2) & 1;
    const int dc = b & 3;
    const int kt = threadIdx.x >> 5;   // 0..15
    const int dt = threadIdx.x & 31;   // 0..31
    const int k0 = kh * 32 + kt * 2;
    const int d0 = dc * 128 + dt * 4;
    const int pixbase = n * 1024;

    float4 a0 = make_float4(0.f, 0.f, 0.f, 0.f);
    float4 a1 = make_float4(0.f, 0.f, 0.f, 0.f);
    const float* xp = x + (size_t)pixbase * 512 + d0;
    const float* sp = s + (size_t)pixbase * 64 + k0;
#pragma unroll 4
    for (int p = 0; p < 1024; ++p) {
        float4 xv = *(const float4*)(xp + (size_t)p * 512);
        float2 sv = *(const float2*)(sp + (size_t)p * 64);
        a0.x = fmaf(sv.x, xv.x, a0.x); a0.y = fmaf(sv.x, xv.y, a0.y);
        a0.z = fmaf(sv.x, xv.z, a0.z); a0.w = fmaf(sv.x, xv.w, a0.w);
        a1.x = fmaf(sv.y, xv.x, a1.x); a1.y = fmaf(sv.y, xv.y, a1.y);
        a1.z = fmaf(sv.y, xv.z, a1.z); a1.w = fmaf(sv.y, xv.w, a1.w);
    }
    float* vp = v + ((size_t)(n * 64 + k0)) * 512 + d0;
    *(float4*)vp         = a0;
    *(float4*)(vp + 512) = a1;
}

// ---- kernel 3: vn = intra-L2-norm(v + a*C) * 1/8 -------------------------
// grid 512 x 256 (4 waves); one wave per (n,k) row of 512 d.
__global__ __launch_bounds__(256) void k_norm(
    const float* __restrict__ v, const float* __restrict__ ap,
    const float* __restrict__ C, float* __restrict__ vn)
{
    const int lane = threadIdx.x & 63;
    const int w    = threadIdx.x >> 6;
    const int row  = blockIdx.x * 4 + w;   // n*64 + k
    const int n    = row >> 6;
    const int k    = row & 63;

    float a_nk = 0.f;
#pragma unroll
    for (int t = 0; t < 16; ++t)
        a_nk += ap[((size_t)(n * 16 + t)) * 64 + k];

    const float* vr = v + (size_t)row * 512;
    float vv[8];
    float ss = 0.f;
#pragma unroll
    for (int j = 0; j < 8; ++j) {
        int d = j * 64 + lane;
        float t = vr[d] + a_nk * C[(size_t)d * 64 + k];
        vv[j] = t;
        ss = fmaf(t, t, ss);
    }
#pragma unroll
    for (int off = 32; off > 0; off >>= 1) ss += __shfl_xor(ss, off, 64);
    // intra-norm; global descriptor norm == /8 exactly (64 unit rows)
    const float scale = rsqrtf(fmaxf(ss, EPSF)) * 0.125f;
    float* vo = vn + (size_t)row * 512;
#pragma unroll
    for (int j = 0; j < 8; ++j) vo[j * 64 + lane] = vv[j] * scale;
}

// ---- kernel 4: outpart[kc] = vn @ W2 slice (split-K 16) ------------------
// grid 1024 = kc(16) x cb(64); 256 threads (4 waves). Wave w owns 512 rows;
// lane owns 1 col; 32 f32 acc (all n). Per 32-row group: 32 w2 regs (32
// in-flight coalesced loads) then 32n x 8 float4 uniform vn broadcasts.
// End: 4-wave LDS tree reduce -> one outpart slice per kc.
__global__ __launch_bounds__(256, 4) void k_gemm2(
    const float* __restrict__ vn, const float* __restrict__ w2,
    float* __restrict__ outpart)
{
    const int b    = blockIdx.x;
    const int kc   = b >> 6;
    const int cb   = b & 63;
    const int w    = threadIdx.x >> 6;
    const int lane = threadIdx.x & 63;
    const int col  = cb * 64 + lane;
    const int rbase = kc * 2048 + w * 512;

    float acc[32];
#pragma unroll
    for (int nn = 0; nn < 32; ++nn) acc[nn] = 0.f;

    for (int g = 0; g < 16; ++g) {
        const int r0 = rbase + g * 32;
        float wv[32];
#pragma unroll
        for (int rr = 0; rr < 32; ++rr)
            wv[rr] = w2[(size_t)(r0 + rr) * 4096 + col];
#pragma unroll
        for (int nn = 0; nn < 32; ++nn) {
            const float* vp = vn + (size_t)nn * 32768 + r0;
#pragma unroll
            for (int q = 0; q < 8; ++q) {
                float4 vv = *(const float4*)(vp + q * 4);   // uniform
                acc[nn] = fmaf(vv.x, wv[q * 4 + 0], acc[nn]);
                acc[nn] = fmaf(vv.y, wv[q * 4 + 1], acc[nn]);
                acc[nn] = fmaf(vv.z, wv[q * 4 + 2], acc[nn]);
                acc[nn] = fmaf(vv.w, wv[q * 4 + 3], acc[nn]);
            }
        }
    }

    __shared__ float red[4][64][33];   // +1 pad: lanes land on distinct banks
#pragma unroll
    for (int nn = 0; nn < 32; ++nn) red[w][lane][nn] = acc[nn];
    __syncthreads();
    const int c  = threadIdx.x & 63;
    const int ng = threadIdx.x >> 6;
#pragma unroll
    for (int q = 0; q < 8; ++q) {
        const int nn = ng * 8 + q;
        float sum = red[0][c][nn] + red[1][c][nn] + red[2][c][nn] + red[3][c][nn];
        outpart[(size_t)kc * 131072 + (size_t)nn * 4096 + cb * 64 + c] = sum;
    }
}

// ---- kernel 5: reduce 16 partials + bias, per-block sumsq ----------------
__global__ __launch_bounds__(256) void k_reduce(
    const float* __restrict__ outpart, const float* __restrict__ b2,
    float* __restrict__ out, float* __restrict__ ssp)
{
    const int i = (blockIdx.x * 256 + threadIdx.x) * 4;
    float4 o = make_float4(0.f, 0.f, 0.f, 0.f);
#pragma unroll
    for (int kc = 0; kc < 16; ++kc) {
        float4 t = *(const float4*)&outpart[(size_t)kc * 131072 + i];
        o.x += t.x; o.y += t.y; o.z += t.z; o.w += t.w;
    }
    float4 bb = *(const float4*)&b2[i & 4095];
    o.x += bb.x; o.y += bb.y; o.z += bb.z; o.w += bb.w;
    *(float4*)&out[i] = o;

    float ss = o.x * o.x + o.y * o.y + o.z * o.z + o.w * o.w;
#pragma unroll
    for (int off = 32; off > 0; off >>= 1) ss += __shfl_xor(ss, off, 64);
    __shared__ float lred[4];
    if ((threadIdx.x & 63) == 0) lred[threadIdx.x >> 6] = ss;
    __syncthreads();
    if (threadIdx.x == 0)
        ssp[blockIdx.x] = lred[0] + lred[1] + lred[2] + lred[3];
}

// ---- kernel 6: global L2 scale (redundant ssp sum, deterministic) --------
__global__ __launch_bounds__(256) void k_scale(
    const float* __restrict__ ssp, float* __restrict__ out)
{
    float ss = 0.f;
#pragma unroll
    for (int t = 0; t < 128; ++t) ss += ssp[t];
    const float sc = rsqrtf(fmaxf(ss, EPSF));
    const int i = (blockIdx.x * 256 + threadIdx.x) * 4;
    float4 o = *(float4*)&out[i];
    o.x *= sc; o.y *= sc; o.z *= sc; o.w *= sc;
    *(float4*)&out[i] = o;
}

extern "C" void kernel_launch(void* const* d_in, const int* in_sizes, int n_in,
                              void* d_out, int out_size, void* d_ws, size_t ws_size,
                              hipStream_t stream)
{
    const float* x  = (const float*)d_in[0];
    const float* w1 = (const float*)d_in[1];
    const float* b1 = (const float*)d_in[2];
    const float* C  = (const float*)d_in[3];
    const float* w2 = (const float*)d_in[4];
    const float* b2 = (const float*)d_in[5];
    float* out = (float*)d_out;
    float* ws  = (float*)d_ws;

    // ws layout (floats) — PEAK 12.13 MiB (prev 21.1 MiB overran ws_size,
    // corrupting a neighboring input buffer -> post-timing divergence):
    //   s       [0,       2M)        phases 1-2
    //   v       [2M,      3M)        phases 2-3
    //   ap      [3M,      3M+32768)  phases 1-3
    //   vn      [0,       1M)        phases 3-4 (over dead s)
    //   outpart [1M,      3M)        phases 4-5 (over dead s-top + v), kc=16
    //   ssp     [3M+32768, +128)     phases 5-6
    float* s_buf   = ws;
    float* v_buf   = ws + 2097152;
    float* ap      = ws + 3145728;
    float* vn      = ws;
    float* outpart = ws + 1048576;
    float* ssp     = ws + 3145728 + 32768;

    k_assign<<<512,  256, 0, stream>>>(x, w1, b1, s_buf, ap);
    k_vlad  <<<256,  512, 0, stream>>>(s_buf, x, v_buf);
    k_norm  <<<512,  256, 0, stream>>>(v_buf, ap, C, vn);
    k_gemm2 <<<1024, 256, 0, stream>>>(vn, w2, outpart);
    k_reduce<<<128,  256, 0, stream>>>(outpart, b2, out, ssp);
    k_scale <<<128,  256, 0, stream>>>(ssp, out);
}

// Round 3
// 874.796 us; speedup vs baseline: 1.1173x; 1.1173x over previous
//
#include <hip/hip_runtime.h>
#include <math.h>

#define EPSF 1e-12f
// N=32, HW=1024, D=512, K=64, OUT=4096, KD=32768

// ---- kernel 1: s = softmax(x @ W1 + b1); ap = per-block column sums -------
// grid 512 x 256 (4 waves). Block owns 64 pixels (lane=pixel); wave h owns
// k-range [h*16, h*16+16). x staged in LDS (coalesced); w1/b1 wave-uniform
// (readfirstlane'd base -> scalar loads).
__global__ __launch_bounds__(256) void k_assign(
    const float* __restrict__ x, const float* __restrict__ w1,
    const float* __restrict__ b1, float* __restrict__ s,
    float* __restrict__ ap)
{
    const int tid   = threadIdx.x;
    const int lane  = tid & 63;
    const int h     = __builtin_amdgcn_readfirstlane(tid >> 6);  // 0..3
    const int pix0  = blockIdx.x * 64;
    const int kbase = h * 16;

    __shared__ float Xs[64][65];            // +1 pad: (l+dd)%32 banks, 2-way
    __shared__ float redm[4][64];
    __shared__ float reds[4][64];

    float acc[16];
#pragma unroll
    for (int i = 0; i < 16; ++i) acc[i] = b1[kbase + i];

    for (int c = 0; c < 8; ++c) {           // 8 chunks of 64 d
        __syncthreads();
#pragma unroll
        for (int t = 0; t < 4; ++t) {       // stage 64px x 64d, coalesced
            int idx = tid + t * 256;        // 0..1023 float4 slots
            int p   = idx >> 4;
            int d4  = (idx & 15) << 2;
            float4 xv = *(const float4*)&x[(size_t)(pix0 + p) * 512 + c * 64 + d4];
            Xs[p][d4]     = xv.x; Xs[p][d4 + 1] = xv.y;
            Xs[p][d4 + 2] = xv.z; Xs[p][d4 + 3] = xv.w;
        }
        __syncthreads();
        const float* wc = w1 + (size_t)c * 64 * 64 + kbase;   // uniform
#pragma unroll 4
        for (int dd = 0; dd < 64; ++dd) {
            float xs = Xs[lane][dd];
            const float* wr = wc + (size_t)dd * 64;
#pragma unroll
            for (int kk = 0; kk < 16; ++kk)
                acc[kk] = fmaf(xs, wr[kk], acc[kk]);
        }
    }

    // softmax over 64 k (cross-wave exchange through LDS)
    float m = acc[0];
#pragma unroll
    for (int i = 1; i < 16; ++i) m = fmaxf(m, acc[i]);
    redm[h][lane] = m;
    __syncthreads();
    m = fmaxf(fmaxf(redm[0][lane], redm[1][lane]),
              fmaxf(redm[2][lane], redm[3][lane]));
    float sum = 0.f;
#pragma unroll
    for (int i = 0; i < 16; ++i) { acc[i] = __expf(acc[i] - m); sum += acc[i]; }
    reds[h][lane] = sum;
    __syncthreads();
    const float inv = 1.0f / (reds[0][lane] + reds[1][lane] +
                              reds[2][lane] + reds[3][lane]);
#pragma unroll
    for (int i = 0; i < 16; ++i) acc[i] *= inv;

    float* srow = s + (size_t)(pix0 + lane) * 64 + kbase;
#pragma unroll
    for (int i = 0; i < 16; i += 4)
        *(float4*)(srow + i) = make_float4(acc[i], acc[i+1], acc[i+2], acc[i+3]);

#pragma unroll
    for (int i = 0; i < 16; ++i) {
        float v = acc[i];
#pragma unroll
        for (int off = 32; off > 0; off >>= 1) v += __shfl_xor(v, off, 64);
        if (lane == 0) ap[(size_t)blockIdx.x * 64 + kbase + i] = v;
    }
}

// ---- kernel 2: v[n,k,d] = sum_p s[p,k] * x[p,d] ---------------------------
// grid 256 = n(32) x dc(8); 512 threads (8 waves). Thread: 2 k x 4 d,
// all 1024 pixels. 8 FMA per 2 loads; s/x rows broadcast through L1.
__global__ __launch_bounds__(512) void k_vlad(
    const float* __restrict__ s, const float* __restrict__ x,
    float* __restrict__ v)
{
    const int b  = blockIdx.x;
    const int n  = b >> 3;
    const int dc = b & 7;
    const int kt = threadIdx.x >> 4;       // 0..31
    const int dt = threadIdx.x & 15;       // 0..15
    const int k0 = kt * 2;
    const int d0 = dc * 64 + dt * 4;
    const int pixbase = n * 1024;

    float4 a0 = make_float4(0.f, 0.f, 0.f, 0.f);
    float4 a1 = make_float4(0.f, 0.f, 0.f, 0.f);
    const float* xp = x + (size_t)pixbase * 512 + d0;
    const float* sp = s + (size_t)pixbase * 64 + k0;
#pragma unroll 4
    for (int p = 0; p < 1024; ++p) {
        float4 xv = *(const float4*)(xp + (size_t)p * 512);
        float2 sv = *(const float2*)(sp + (size_t)p * 64);
        a0.x = fmaf(sv.x, xv.x, a0.x); a0.y = fmaf(sv.x, xv.y, a0.y);
        a0.z = fmaf(sv.x, xv.z, a0.z); a0.w = fmaf(sv.x, xv.w, a0.w);
        a1.x = fmaf(sv.y, xv.x, a1.x); a1.y = fmaf(sv.y, xv.y, a1.y);
        a1.z = fmaf(sv.y, xv.z, a1.z); a1.w = fmaf(sv.y, xv.w, a1.w);
    }
    float* vp = v + ((size_t)(n * 64 + k0)) * 512 + d0;
    *(float4*)vp         = a0;
    *(float4*)(vp + 512) = a1;
}

// ---- kernel 3: vn = intra-L2-norm(v + a*C) * 1/8 --------------------------
// grid 512 x 256 (4 waves); one wave per (n,k) row of 512 d.
__global__ __launch_bounds__(256) void k_norm(
    const float* __restrict__ v, const float* __restrict__ ap,
    const float* __restrict__ C, float* __restrict__ vn)
{
    const int lane = threadIdx.x & 63;
    const int w    = threadIdx.x >> 6;
    const int row  = blockIdx.x * 4 + w;   // n*64 + k
    const int n    = row >> 6;
    const int k    = row & 63;

    float a_nk = 0.f;
#pragma unroll
    for (int t = 0; t < 16; ++t)
        a_nk += ap[((size_t)(n * 16 + t)) * 64 + k];

    const float* vr = v + (size_t)row * 512;
    float vv[8];
    float ss = 0.f;
#pragma unroll
    for (int j = 0; j < 8; ++j) {
        int d = j * 64 + lane;
        float t = vr[d] + a_nk * C[(size_t)d * 64 + k];
        vv[j] = t;
        ss = fmaf(t, t, ss);
    }
#pragma unroll
    for (int off = 32; off > 0; off >>= 1) ss += __shfl_xor(ss, off, 64);
    // intra-norm; global descriptor norm == /8 exactly (64 unit rows)
    const float scale = rsqrtf(fmaxf(ss, EPSF)) * 0.125f;
    float* vo = vn + (size_t)row * 512;
#pragma unroll
    for (int j = 0; j < 8; ++j) vo[j * 64 + lane] = vv[j] * scale;
}

// ---- kernel 4: outpart[kc] = vn @ W2 slice (split-K 16) -------------------
// grid 512 = kc(16) x cb(32); 256 threads (4 waves). Thread: 1 col (of 128
// per block) x 32 n acc; row-half h (readfirstlane -> wave-uniform, enables
// s_load for vn). 16-row groups: wv[16] coalesced w2 loads in flight, then
// 32n x 4 float4 uniform vn reads. Halves reduced via padded LDS.
// Register plan: acc32 + wv16 + 16 transient ~= 96 VGPR, no spill.
__global__ __launch_bounds__(256, 2) void k_gemm2(
    const float* __restrict__ vn, const float* __restrict__ w2,
    float* __restrict__ outpart)
{
    const int b    = blockIdx.x;
    const int kc   = b >> 5;
    const int cb   = b & 31;
    const int tid  = threadIdx.x;
    const int colt = tid & 127;
    const int h    = __builtin_amdgcn_readfirstlane(tid >> 7);  // 0/1
    const int col  = cb * 128 + colt;
    const int r0   = kc * 2048 + h * 1024;

    float acc[32];
#pragma unroll
    for (int nn = 0; nn < 32; ++nn) acc[nn] = 0.f;

    const float* wp = w2 + (size_t)r0 * 4096 + col;
    for (int g = 0; g < 64; ++g) {          // 64 groups of 16 rows
        float wv[16];
#pragma unroll
        for (int rr = 0; rr < 16; ++rr)
            wv[rr] = wp[(size_t)(g * 16 + rr) * 4096];
#pragma unroll
        for (int nn = 0; nn < 32; ++nn) {
            const float* vp = vn + (size_t)nn * 32768 + r0 + g * 16; // uniform
            float4 v0 = *(const float4*)(vp);
            float4 v1 = *(const float4*)(vp + 4);
            float4 v2 = *(const float4*)(vp + 8);
            float4 v3 = *(const float4*)(vp + 12);
            acc[nn] = fmaf(v0.x, wv[0],  acc[nn]);
            acc[nn] = fmaf(v0.y, wv[1],  acc[nn]);
            acc[nn] = fmaf(v0.z, wv[2],  acc[nn]);
            acc[nn] = fmaf(v0.w, wv[3],  acc[nn]);
            acc[nn] = fmaf(v1.x, wv[4],  acc[nn]);
            acc[nn] = fmaf(v1.y, wv[5],  acc[nn]);
            acc[nn] = fmaf(v1.z, wv[6],  acc[nn]);
            acc[nn] = fmaf(v1.w, wv[7],  acc[nn]);
            acc[nn] = fmaf(v2.x, wv[8],  acc[nn]);
            acc[nn] = fmaf(v2.y, wv[9],  acc[nn]);
            acc[nn] = fmaf(v2.z, wv[10], acc[nn]);
            acc[nn] = fmaf(v2.w, wv[11], acc[nn]);
            acc[nn] = fmaf(v3.x, wv[12], acc[nn]);
            acc[nn] = fmaf(v3.y, wv[13], acc[nn]);
            acc[nn] = fmaf(v3.z, wv[14], acc[nn]);
            acc[nn] = fmaf(v3.w, wv[15], acc[nn]);
        }
    }

    __shared__ float red[128][33];          // +1 pad: (colt+nn)%32, no conflict
    if (h == 1) {
#pragma unroll
        for (int nn = 0; nn < 32; ++nn) red[colt][nn] = acc[nn];
    }
    __syncthreads();
    if (h == 0) {
#pragma unroll
        for (int nn = 0; nn < 32; ++nn) {
            float sum = acc[nn] + red[colt][nn];
            outpart[(size_t)kc * 131072 + (size_t)nn * 4096 + col] = sum;
        }
    }
}

// ---- kernel 5: reduce 16 partials + bias, per-block sumsq -----------------
__global__ __launch_bounds__(256) void k_reduce(
    const float* __restrict__ outpart, const float* __restrict__ b2,
    float* __restrict__ out, float* __restrict__ ssp)
{
    const int i = (blockIdx.x * 256 + threadIdx.x) * 4;
    float4 o = make_float4(0.f, 0.f, 0.f, 0.f);
#pragma unroll
    for (int kc = 0; kc < 16; ++kc) {
        float4 t = *(const float4*)&outpart[(size_t)kc * 131072 + i];
        o.x += t.x; o.y += t.y; o.z += t.z; o.w += t.w;
    }
    float4 bb = *(const float4*)&b2[i & 4095];
    o.x += bb.x; o.y += bb.y; o.z += bb.z; o.w += bb.w;
    *(float4*)&out[i] = o;

    float ss = o.x * o.x + o.y * o.y + o.z * o.z + o.w * o.w;
#pragma unroll
    for (int off = 32; off > 0; off >>= 1) ss += __shfl_xor(ss, off, 64);
    __shared__ float lred[4];
    if ((threadIdx.x & 63) == 0) lred[threadIdx.x >> 6] = ss;
    __syncthreads();
    if (threadIdx.x == 0)
        ssp[blockIdx.x] = lred[0] + lred[1] + lred[2] + lred[3];
}

// ---- kernel 6: global L2 scale (redundant ssp sum, deterministic) ---------
__global__ __launch_bounds__(256) void k_scale(
    const float* __restrict__ ssp, float* __restrict__ out)
{
    float ss = 0.f;
#pragma unroll
    for (int t = 0; t < 128; ++t) ss += ssp[t];
    const float sc = rsqrtf(fmaxf(ss, EPSF));
    const int i = (blockIdx.x * 256 + threadIdx.x) * 4;
    float4 o = *(float4*)&out[i];
    o.x *= sc; o.y *= sc; o.z *= sc; o.w *= sc;
    *(float4*)&out[i] = o;
}

extern "C" void kernel_launch(void* const* d_in, const int* in_sizes, int n_in,
                              void* d_out, int out_size, void* d_ws, size_t ws_size,
                              hipStream_t stream)
{
    const float* x  = (const float*)d_in[0];
    const float* w1 = (const float*)d_in[1];
    const float* b1 = (const float*)d_in[2];
    const float* C  = (const float*)d_in[3];
    const float* w2 = (const float*)d_in[4];
    const float* b2 = (const float*)d_in[5];
    float* out = (float*)d_out;
    float* ws  = (float*)d_ws;

    // ws layout (floats) — peak 12.13 MiB (proven budget):
    //   s       [0,       2M)        phases 1-2
    //   v       [2M,      3M)        phases 2-3
    //   ap      [3M,      3M+32768)  phases 1-3
    //   ssp     [3M+32768, +128)     phases 5-6
    //   vn      [0,       1M)        phases 3-4 (over dead s)
    //   outpart [1M,      3M)        phases 4-5 (over dead s-top + v)
    float* s_buf   = ws;
    float* v_buf   = ws + 2097152;
    float* ap      = ws + 3145728;
    float* ssp     = ws + 3145728 + 32768;
    float* vn      = ws;
    float* outpart = ws + 1048576;

    k_assign<<<512, 256, 0, stream>>>(x, w1, b1, s_buf, ap);
    k_vlad  <<<256, 512, 0, stream>>>(s_buf, x, v_buf);
    k_norm  <<<512, 256, 0, stream>>>(v_buf, ap, C, vn);
    k_gemm2 <<<512, 256, 0, stream>>>(vn, w2, outpart);
    k_reduce<<<128, 256, 0, stream>>>(outpart, b2, out, ssp);
    k_scale <<<128, 256, 0, stream>>>(ssp, out);
}

// Round 4
// 738.603 us; speedup vs baseline: 1.3234x; 1.1844x over previous
//
#include <hip/hip_runtime.h>
#include <math.h>

#define EPSF 1e-12f
// N=32, HW=1024, D=512, K=64, OUT=4096, KD=32768

// ---- kernel 1: s = softmax(x @ W1 + b1); ap = per-block column sums -------
// grid 512 x 256 (4 waves). Block owns 64 pixels (lane=pixel); wave h owns
// k-range [h*16, h*16+16). x staged in LDS (coalesced); w1/b1 wave-uniform.
__global__ __launch_bounds__(256) void k_assign(
    const float* __restrict__ x, const float* __restrict__ w1,
    const float* __restrict__ b1, float* __restrict__ s,
    float* __restrict__ ap)
{
    const int tid   = threadIdx.x;
    const int lane  = tid & 63;
    const int h     = __builtin_amdgcn_readfirstlane(tid >> 6);  // 0..3
    const int pix0  = blockIdx.x * 64;
    const int kbase = h * 16;

    __shared__ float Xs[64][65];
    __shared__ float redm[4][64];
    __shared__ float reds[4][64];

    float acc[16];
#pragma unroll
    for (int i = 0; i < 16; ++i) acc[i] = b1[kbase + i];

    for (int c = 0; c < 8; ++c) {
        __syncthreads();
#pragma unroll
        for (int t = 0; t < 4; ++t) {
            int idx = tid + t * 256;
            int p   = idx >> 4;
            int d4  = (idx & 15) << 2;
            float4 xv = *(const float4*)&x[(size_t)(pix0 + p) * 512 + c * 64 + d4];
            Xs[p][d4]     = xv.x; Xs[p][d4 + 1] = xv.y;
            Xs[p][d4 + 2] = xv.z; Xs[p][d4 + 3] = xv.w;
        }
        __syncthreads();
        const float* wc = w1 + (size_t)c * 64 * 64 + kbase;
#pragma unroll 4
        for (int dd = 0; dd < 64; ++dd) {
            float xs = Xs[lane][dd];
            const float* wr = wc + (size_t)dd * 64;
#pragma unroll
            for (int kk = 0; kk < 16; ++kk)
                acc[kk] = fmaf(xs, wr[kk], acc[kk]);
        }
    }

    float m = acc[0];
#pragma unroll
    for (int i = 1; i < 16; ++i) m = fmaxf(m, acc[i]);
    redm[h][lane] = m;
    __syncthreads();
    m = fmaxf(fmaxf(redm[0][lane], redm[1][lane]),
              fmaxf(redm[2][lane], redm[3][lane]));
    float sum = 0.f;
#pragma unroll
    for (int i = 0; i < 16; ++i) { acc[i] = __expf(acc[i] - m); sum += acc[i]; }
    reds[h][lane] = sum;
    __syncthreads();
    const float inv = 1.0f / (reds[0][lane] + reds[1][lane] +
                              reds[2][lane] + reds[3][lane]);
#pragma unroll
    for (int i = 0; i < 16; ++i) acc[i] *= inv;

    float* srow = s + (size_t)(pix0 + lane) * 64 + kbase;
#pragma unroll
    for (int i = 0; i < 16; i += 4)
        *(float4*)(srow + i) = make_float4(acc[i], acc[i+1], acc[i+2], acc[i+3]);

#pragma unroll
    for (int i = 0; i < 16; ++i) {
        float v = acc[i];
#pragma unroll
        for (int off = 32; off > 0; off >>= 1) v += __shfl_xor(v, off, 64);
        if (lane == 0) ap[(size_t)blockIdx.x * 64 + kbase + i] = v;
    }
}

// ---- kernel 2: v[n,k,d] = sum_p s[p,k] * x[p,d] ---------------------------
__global__ __launch_bounds__(512) void k_vlad(
    const float* __restrict__ s, const float* __restrict__ x,
    float* __restrict__ v)
{
    const int b  = blockIdx.x;
    const int n  = b >> 3;
    const int dc = b & 7;
    const int kt = threadIdx.x >> 4;
    const int dt = threadIdx.x & 15;
    const int k0 = kt * 2;
    const int d0 = dc * 64 + dt * 4;
    const int pixbase = n * 1024;

    float4 a0 = make_float4(0.f, 0.f, 0.f, 0.f);
    float4 a1 = make_float4(0.f, 0.f, 0.f, 0.f);
    const float* xp = x + (size_t)pixbase * 512 + d0;
    const float* sp = s + (size_t)pixbase * 64 + k0;
#pragma unroll 4
    for (int p = 0; p < 1024; ++p) {
        float4 xv = *(const float4*)(xp + (size_t)p * 512);
        float2 sv = *(const float2*)(sp + (size_t)p * 64);
        a0.x = fmaf(sv.x, xv.x, a0.x); a0.y = fmaf(sv.x, xv.y, a0.y);
        a0.z = fmaf(sv.x, xv.z, a0.z); a0.w = fmaf(sv.x, xv.w, a0.w);
        a1.x = fmaf(sv.y, xv.x, a1.x); a1.y = fmaf(sv.y, xv.y, a1.y);
        a1.z = fmaf(sv.y, xv.z, a1.z); a1.w = fmaf(sv.y, xv.w, a1.w);
    }
    float* vp = v + ((size_t)(n * 64 + k0)) * 512 + d0;
    *(float4*)vp         = a0;
    *(float4*)(vp + 512) = a1;
}

// ---- kernel 3: vn = intra-L2-norm(v + a*C) * 1/8 --------------------------
__global__ __launch_bounds__(256) void k_norm(
    const float* __restrict__ v, const float* __restrict__ ap,
    const float* __restrict__ C, float* __restrict__ vn)
{
    const int lane = threadIdx.x & 63;
    const int w    = threadIdx.x >> 6;
    const int row  = blockIdx.x * 4 + w;   // n*64 + k
    const int n    = row >> 6;
    const int k    = row & 63;

    float a_nk = 0.f;
#pragma unroll
    for (int t = 0; t < 16; ++t)
        a_nk += ap[((size_t)(n * 16 + t)) * 64 + k];

    const float* vr = v + (size_t)row * 512;
    float vv[8];
    float ss = 0.f;
#pragma unroll
    for (int j = 0; j < 8; ++j) {
        int d = j * 64 + lane;
        float t = vr[d] + a_nk * C[(size_t)d * 64 + k];
        vv[j] = t;
        ss = fmaf(t, t, ss);
    }
#pragma unroll
    for (int off = 32; off > 0; off >>= 1) ss += __shfl_xor(ss, off, 64);
    const float scale = rsqrtf(fmaxf(ss, EPSF)) * 0.125f;
    float* vo = vn + (size_t)row * 512;
#pragma unroll
    for (int j = 0; j < 8; ++j) vo[j * 64 + lane] = vv[j] * scale;
}

// ---- kernel 4: outpart[kc] = vn @ W2 slice --------------------------------
// grid 256 = kc(16) x cb(16); 256 thr (4 waves stacked over rows).
// Wave w: rows [kc*2048+w*512, +512), lane owns 4 contiguous cols of
// [cb*256, +256). acc4[32] (128 VGPR) = 32 n x 4 cols. w2 streamed via
// 3-deep software pipeline of 4-row float4 groups (named A/B/C bufs,
// 2 groups = 128 B/thread in flight -> 32 KB/CU, Little's-law saturating).
// vn read as s_load_dwordx4 per n (uniform addr), 8-n batches under the
// ~102-SGPR/wave cap. Epilogue: chunked LDS reduce of 4 row-slices.
__device__ __forceinline__ void load_group(const float* __restrict__ wpg,
                                           float4* __restrict__ B)
{
    B[0] = *(const float4*)(wpg);
    B[1] = *(const float4*)(wpg + 4096);
    B[2] = *(const float4*)(wpg + 8192);
    B[3] = *(const float4*)(wpg + 12288);
}

__device__ __forceinline__ void consume_group(const float* __restrict__ vpg,
                                              const float4* __restrict__ B,
                                              float4* __restrict__ acc4)
{
#pragma unroll
    for (int nn = 0; nn < 32; ++nn) {
        float4 vv = *(const float4*)(vpg + (size_t)nn * 32768);  // uniform
        acc4[nn].x = fmaf(vv.x, B[0].x, acc4[nn].x);
        acc4[nn].y = fmaf(vv.x, B[0].y, acc4[nn].y);
        acc4[nn].z = fmaf(vv.x, B[0].z, acc4[nn].z);
        acc4[nn].w = fmaf(vv.x, B[0].w, acc4[nn].w);
        acc4[nn].x = fmaf(vv.y, B[1].x, acc4[nn].x);
        acc4[nn].y = fmaf(vv.y, B[1].y, acc4[nn].y);
        acc4[nn].z = fmaf(vv.y, B[1].z, acc4[nn].z);
        acc4[nn].w = fmaf(vv.y, B[1].w, acc4[nn].w);
        acc4[nn].x = fmaf(vv.z, B[2].x, acc4[nn].x);
        acc4[nn].y = fmaf(vv.z, B[2].y, acc4[nn].y);
        acc4[nn].z = fmaf(vv.z, B[2].z, acc4[nn].z);
        acc4[nn].w = fmaf(vv.z, B[2].w, acc4[nn].w);
        acc4[nn].x = fmaf(vv.w, B[3].x, acc4[nn].x);
        acc4[nn].y = fmaf(vv.w, B[3].y, acc4[nn].y);
        acc4[nn].z = fmaf(vv.w, B[3].z, acc4[nn].z);
        acc4[nn].w = fmaf(vv.w, B[3].w, acc4[nn].w);
    }
}

__global__ __launch_bounds__(256, 2) void k_gemm2(
    const float* __restrict__ vn, const float* __restrict__ w2,
    float* __restrict__ outpart)
{
    const int b    = blockIdx.x;
    const int kc   = b >> 4;
    const int cb   = b & 15;
    const int tid  = threadIdx.x;
    const int lane = tid & 63;
    const int w    = __builtin_amdgcn_readfirstlane(tid >> 6);  // 0..3
    const int col  = cb * 256 + lane * 4;
    const int r0   = kc * 2048 + w * 512;

    float4 acc4[32];
#pragma unroll
    for (int nn = 0; nn < 32; ++nn) acc4[nn] = make_float4(0.f, 0.f, 0.f, 0.f);

    const float* wp = w2 + (size_t)r0 * 4096 + col;
    const float* vp = vn + r0;

    float4 A[4], Bb[4], Cc[4];
    load_group(wp,             A);
    load_group(wp + 16384,     Bb);
    load_group(wp + 32768,     Cc);

    // 128 groups of 4 rows; 3-stage rotation, steady state 2 groups in flight
    for (int g = 0; g < 123; g += 3) {
        consume_group(vp + (size_t)g * 4,       A,  acc4);
        load_group(wp + (size_t)(g + 3) * 16384, A);
        consume_group(vp + (size_t)(g + 1) * 4, Bb, acc4);
        load_group(wp + (size_t)(g + 4) * 16384, Bb);
        consume_group(vp + (size_t)(g + 2) * 4, Cc, acc4);
        load_group(wp + (size_t)(g + 5) * 16384, Cc);
    }
    consume_group(vp + 123 * 4, A,  acc4);
    load_group(wp + (size_t)126 * 16384, A);
    consume_group(vp + 124 * 4, Bb, acc4);
    load_group(wp + (size_t)127 * 16384, Bb);
    consume_group(vp + 125 * 4, Cc, acc4);
    consume_group(vp + 126 * 4, A,  acc4);
    consume_group(vp + 127 * 4, Bb, acc4);

    // reduce the 4 row-slices (waves) in 4 chunks of 8 n
    __shared__ float4 red[4][64][8];   // 32 KB
#pragma unroll
    for (int chunk = 0; chunk < 4; ++chunk) {
        __syncthreads();
#pragma unroll
        for (int q = 0; q < 8; ++q) red[w][lane][q] = acc4[chunk * 8 + q];
        __syncthreads();
#pragma unroll
        for (int item = 0; item < 2; ++item) {
            int i    = tid + item * 256;
            int l2   = i & 63;
            int q2   = i >> 6;         // 0..7
            float4 s0 = red[0][l2][q2];
            float4 s1 = red[1][l2][q2];
            float4 s2 = red[2][l2][q2];
            float4 s3 = red[3][l2][q2];
            float4 o;
            o.x = (s0.x + s1.x) + (s2.x + s3.x);
            o.y = (s0.y + s1.y) + (s2.y + s3.y);
            o.z = (s0.z + s1.z) + (s2.z + s3.z);
            o.w = (s0.w + s1.w) + (s2.w + s3.w);
            int n = chunk * 8 + q2;
            *(float4*)&outpart[(size_t)kc * 131072 + (size_t)n * 4096 +
                               cb * 256 + l2 * 4] = o;
        }
    }
}

// ---- kernel 5: reduce 16 partials + bias, per-block sumsq -----------------
__global__ __launch_bounds__(256) void k_reduce(
    const float* __restrict__ outpart, const float* __restrict__ b2,
    float* __restrict__ out, float* __restrict__ ssp)
{
    const int i = (blockIdx.x * 256 + threadIdx.x) * 4;
    float4 o = make_float4(0.f, 0.f, 0.f, 0.f);
#pragma unroll
    for (int kc = 0; kc < 16; ++kc) {
        float4 t = *(const float4*)&outpart[(size_t)kc * 131072 + i];
        o.x += t.x; o.y += t.y; o.z += t.z; o.w += t.w;
    }
    float4 bb = *(const float4*)&b2[i & 4095];
    o.x += bb.x; o.y += bb.y; o.z += bb.z; o.w += bb.w;
    *(float4*)&out[i] = o;

    float ss = o.x * o.x + o.y * o.y + o.z * o.z + o.w * o.w;
#pragma unroll
    for (int off = 32; off > 0; off >>= 1) ss += __shfl_xor(ss, off, 64);
    __shared__ float lred[4];
    if ((threadIdx.x & 63) == 0) lred[threadIdx.x >> 6] = ss;
    __syncthreads();
    if (threadIdx.x == 0)
        ssp[blockIdx.x] = lred[0] + lred[1] + lred[2] + lred[3];
}

// ---- kernel 6: global L2 scale ---------------------------------------------
__global__ __launch_bounds__(256) void k_scale(
    const float* __restrict__ ssp, float* __restrict__ out)
{
    float ss = 0.f;
#pragma unroll
    for (int t = 0; t < 128; ++t) ss += ssp[t];
    const float sc = rsqrtf(fmaxf(ss, EPSF));
    const int i = (blockIdx.x * 256 + threadIdx.x) * 4;
    float4 o = *(float4*)&out[i];
    o.x *= sc; o.y *= sc; o.z *= sc; o.w *= sc;
    *(float4*)&out[i] = o;
}

extern "C" void kernel_launch(void* const* d_in, const int* in_sizes, int n_in,
                              void* d_out, int out_size, void* d_ws, size_t ws_size,
                              hipStream_t stream)
{
    const float* x  = (const float*)d_in[0];
    const float* w1 = (const float*)d_in[1];
    const float* b1 = (const float*)d_in[2];
    const float* C  = (const float*)d_in[3];
    const float* w2 = (const float*)d_in[4];
    const float* b2 = (const float*)d_in[5];
    float* out = (float*)d_out;
    float* ws  = (float*)d_ws;

    // ws layout (floats) — peak 12.13 MiB (proven budget):
    //   s       [0,       2M)        phases 1-2
    //   v       [2M,      3M)        phases 2-3
    //   ap      [3M,      3M+32768)  phases 1-3
    //   ssp     [3M+32768, +128)     phases 5-6
    //   vn      [0,       1M)        phases 3-4 (over dead s)
    //   outpart [1M,      3M)        phases 4-5 (over dead s-top + v)
    float* s_buf   = ws;
    float* v_buf   = ws + 2097152;
    float* ap      = ws + 3145728;
    float* ssp     = ws + 3145728 + 32768;
    float* vn      = ws;
    float* outpart = ws + 1048576;

    k_assign<<<512, 256, 0, stream>>>(x, w1, b1, s_buf, ap);
    k_vlad  <<<256, 512, 0, stream>>>(s_buf, x, v_buf);
    k_norm  <<<512, 256, 0, stream>>>(v_buf, ap, C, vn);
    k_gemm2 <<<256, 256, 0, stream>>>(vn, w2, outpart);
    k_reduce<<<128, 256, 0, stream>>>(outpart, b2, out, ssp);
    k_scale <<<128, 256, 0, stream>>>(ssp, out);
}

// Round 5
// 603.424 us; speedup vs baseline: 1.6198x; 1.2240x over previous
//
#include <hip/hip_runtime.h>
#include <math.h>

#define EPSF 1e-12f
// N=32, HW=1024, D=512, K=64, OUT=4096, KD=32768

// ---- kernel 1: s = softmax(x @ W1 + b1); ap = per-block column sums -------
// grid 512 x 256 (4 waves). Block owns 64 pixels (lane=pixel); wave h owns
// k-range [h*16, +16). Per 64-d chunk BOTH x and w1 are staged in LDS
// (round-3 version chained ~200cy scalar w1 loads per dd -> latency-bound).
__global__ __launch_bounds__(256) void k_assign(
    const float* __restrict__ x, const float* __restrict__ w1,
    const float* __restrict__ b1, float* __restrict__ s,
    float* __restrict__ ap)
{
    const int tid   = threadIdx.x;
    const int lane  = tid & 63;
    const int h     = __builtin_amdgcn_readfirstlane(tid >> 6);  // 0..3
    const int pix0  = blockIdx.x * 64;
    const int kbase = h * 16;

    __shared__ float Xs[64][68];   // px x dd   (+pad)
    __shared__ float Ws[64][68];   // dd x k    (+pad)
    __shared__ float redm[4][64];
    __shared__ float reds[4][64];

    float acc[16];
#pragma unroll
    for (int i = 0; i < 16; ++i) acc[i] = b1[kbase + i];

    for (int c = 0; c < 8; ++c) {
        __syncthreads();
#pragma unroll
        for (int t = 0; t < 4; ++t) {          // stage x: 64px x 64dd
            int idx = tid + t * 256;
            int p   = idx >> 4;
            int d4  = (idx & 15) << 2;
            float4 xv = *(const float4*)&x[(size_t)(pix0 + p) * 512 + c * 64 + d4];
            *(float4*)&Xs[p][d4] = xv;
        }
#pragma unroll
        for (int t = 0; t < 4; ++t) {          // stage w1: 64dd x 64k
            int idx = tid + t * 256;
            int dd  = idx >> 4;
            int k4  = (idx & 15) << 2;
            float4 wv = *(const float4*)&w1[(size_t)(c * 64 + dd) * 64 + k4];
            *(float4*)&Ws[dd][k4] = wv;
        }
        __syncthreads();
#pragma unroll 2
        for (int dd4 = 0; dd4 < 16; ++dd4) {
            float4 xv = *(const float4*)&Xs[lane][dd4 * 4];
#pragma unroll
            for (int ddl = 0; ddl < 4; ++ddl) {
                const float xs = (ddl == 0) ? xv.x : (ddl == 1) ? xv.y :
                                 (ddl == 2) ? xv.z : xv.w;
#pragma unroll
                for (int kk4 = 0; kk4 < 4; ++kk4) {
                    float4 wv = *(const float4*)&Ws[dd4 * 4 + ddl][kbase + kk4 * 4];
                    acc[kk4 * 4 + 0] = fmaf(xs, wv.x, acc[kk4 * 4 + 0]);
                    acc[kk4 * 4 + 1] = fmaf(xs, wv.y, acc[kk4 * 4 + 1]);
                    acc[kk4 * 4 + 2] = fmaf(xs, wv.z, acc[kk4 * 4 + 2]);
                    acc[kk4 * 4 + 3] = fmaf(xs, wv.w, acc[kk4 * 4 + 3]);
                }
            }
        }
    }

    // softmax over 64 k (cross-wave exchange through LDS)
    float m = acc[0];
#pragma unroll
    for (int i = 1; i < 16; ++i) m = fmaxf(m, acc[i]);
    redm[h][lane] = m;
    __syncthreads();
    m = fmaxf(fmaxf(redm[0][lane], redm[1][lane]),
              fmaxf(redm[2][lane], redm[3][lane]));
    float sum = 0.f;
#pragma unroll
    for (int i = 0; i < 16; ++i) { acc[i] = __expf(acc[i] - m); sum += acc[i]; }
    reds[h][lane] = sum;
    __syncthreads();
    const float inv = 1.0f / (reds[0][lane] + reds[1][lane] +
                              reds[2][lane] + reds[3][lane]);
#pragma unroll
    for (int i = 0; i < 16; ++i) acc[i] *= inv;

    float* srow = s + (size_t)(pix0 + lane) * 64 + kbase;
#pragma unroll
    for (int i = 0; i < 16; i += 4)
        *(float4*)(srow + i) = make_float4(acc[i], acc[i+1], acc[i+2], acc[i+3]);

#pragma unroll
    for (int i = 0; i < 16; ++i) {
        float v = acc[i];
#pragma unroll
        for (int off = 32; off > 0; off >>= 1) v += __shfl_xor(v, off, 64);
        if (lane == 0) ap[(size_t)blockIdx.x * 64 + kbase + i] = v;
    }
}

// ---- kernel 2: v[n,k,d] = sum_p s[p,k] * x[p,d] ---------------------------
// grid 512 = n(32) x kh(2) x dc(8); 256 thr. Thread: 2 k x 4 d over 1024 p.
__global__ __launch_bounds__(256) void k_vlad(
    const float* __restrict__ s, const float* __restrict__ x,
    float* __restrict__ v)
{
    const int b  = blockIdx.x;
    const int n  = b >> 4;
    const int kh = (b >> 3) & 1;
    const int dc = b & 7;
    const int kt = threadIdx.x >> 4;       // 0..15
    const int dt = threadIdx.x & 15;       // 0..15
    const int k0 = kh * 32 + kt * 2;
    const int d0 = dc * 64 + dt * 4;
    const int pixbase = n * 1024;

    float4 a0 = make_float4(0.f, 0.f, 0.f, 0.f);
    float4 a1 = make_float4(0.f, 0.f, 0.f, 0.f);
    const float* xp = x + (size_t)pixbase * 512 + d0;
    const float* sp = s + (size_t)pixbase * 64 + k0;
#pragma unroll 4
    for (int p = 0; p < 1024; ++p) {
        float4 xv = *(const float4*)(xp + (size_t)p * 512);
        float2 sv = *(const float2*)(sp + (size_t)p * 64);
        a0.x = fmaf(sv.x, xv.x, a0.x); a0.y = fmaf(sv.x, xv.y, a0.y);
        a0.z = fmaf(sv.x, xv.z, a0.z); a0.w = fmaf(sv.x, xv.w, a0.w);
        a1.x = fmaf(sv.y, xv.x, a1.x); a1.y = fmaf(sv.y, xv.y, a1.y);
        a1.z = fmaf(sv.y, xv.z, a1.z); a1.w = fmaf(sv.y, xv.w, a1.w);
    }
    float* vp = v + ((size_t)(n * 64 + k0)) * 512 + d0;
    *(float4*)vp         = a0;
    *(float4*)(vp + 512) = a1;
}

// ---- kernel 3: vn = intra-L2-norm(v + a*C) * 1/8 --------------------------
__global__ __launch_bounds__(256) void k_norm(
    const float* __restrict__ v, const float* __restrict__ ap,
    const float* __restrict__ C, float* __restrict__ vn)
{
    const int lane = threadIdx.x & 63;
    const int w    = threadIdx.x >> 6;
    const int row  = blockIdx.x * 4 + w;   // n*64 + k
    const int n    = row >> 6;
    const int k    = row & 63;

    float a_nk = 0.f;
#pragma unroll
    for (int t = 0; t < 16; ++t)
        a_nk += ap[((size_t)(n * 16 + t)) * 64 + k];

    const float* vr = v + (size_t)row * 512;
    float vv[8];
    float ss = 0.f;
#pragma unroll
    for (int j = 0; j < 8; ++j) {
        int d = j * 64 + lane;
        float t = vr[d] + a_nk * C[(size_t)d * 64 + k];
        vv[j] = t;
        ss = fmaf(t, t, ss);
    }
#pragma unroll
    for (int off = 32; off > 0; off >>= 1) ss += __shfl_xor(ss, off, 64);
    const float scale = rsqrtf(fmaxf(ss, EPSF)) * 0.125f;
    float* vo = vn + (size_t)row * 512;
#pragma unroll
    for (int j = 0; j < 8; ++j) vo[j * 64 + lane] = vv[j] * scale;
}

// ---- kernel 4: outpart[kc] = vn @ W2 slice --------------------------------
// grid 512 = kc(16) x cb(32); 256 thr (4 waves). Half h = tid>>7 owns 1024
// rows; thread owns 1 col (of 128) x 32 n acc (32 VGPR). w2 streamed via
// global_load_lds (width 16) into double-buffered 32-row LDS tiles — the
// in-flight bytes live in LDS, costing 0 VGPRs (round-4 register pipeline
// spilled 912 MB of scratch). One __syncthreads per tile; its vmcnt(0)
// drain lands after ~2300cy of compute >> ~900cy HBM latency.
// vn read as uniform float4 (s_load_dwordx4, SGPR operand into v_fmac).
__global__ __launch_bounds__(256, 2) void k_gemm2(
    const float* __restrict__ vn, const float* __restrict__ w2,
    float* __restrict__ outpart)
{
    __shared__ float tile[2][2][32][128];   // [half][buf][row][col] = 64 KB

    const int b    = blockIdx.x;
    const int kc   = b >> 5;
    const int cb   = b & 31;
    const int tid  = threadIdx.x;
    const int lane = tid & 63;
    const int colt = tid & 127;
    const int h    = __builtin_amdgcn_readfirstlane(tid >> 7);      // 0/1
    const int wh   = __builtin_amdgcn_readfirstlane((tid >> 6) & 1);// wave in half
    const int dr   = lane >> 5;             // 0/1: row within 2-row instr
    const int c4   = (lane & 31) << 2;      // col within row
    const int rowbase = kc * 2048 + h * 1024;

    float acc[32];
#pragma unroll
    for (int nn = 0; nn < 32; ++nn) acc[nn] = 0.f;

#define STAGE(T_, B_)                                                        \
    do {                                                                     \
        const int rg_ = rowbase + (T_) * 32 + wh * 16;                       \
        const float* gs_ = w2 + (size_t)(rg_ + dr) * 4096 + cb * 128 + c4;   \
        _Pragma("unroll")                                                    \
        for (int i_ = 0; i_ < 8; ++i_) {                                     \
            __builtin_amdgcn_global_load_lds(                                \
                (const __attribute__((address_space(1))) void*)              \
                    (gs_ + (size_t)i_ * 2 * 4096),                           \
                (__attribute__((address_space(3))) void*)                    \
                    &tile[h][B_][wh * 16 + i_ * 2][0],                       \
                16, 0, 0);                                                   \
        }                                                                    \
    } while (0)

    STAGE(0, 0);
    __syncthreads();

    int buf = 0;
    for (int t = 0; t < 32; ++t) {
        if (t + 1 < 32) STAGE(t + 1, buf ^ 1);

        float wreg[32];
#pragma unroll
        for (int r = 0; r < 32; ++r) wreg[r] = tile[h][buf][r][colt];

        const float* vb = vn + rowbase + t * 32;
#pragma unroll
        for (int nn = 0; nn < 32; ++nn) {
            const float* vp = vb + (size_t)nn * 32768;   // wave-uniform
#pragma unroll
            for (int r4 = 0; r4 < 8; ++r4) {
                float4 vv = *(const float4*)(vp + r4 * 4);
                acc[nn] = fmaf(vv.x, wreg[r4 * 4 + 0], acc[nn]);
                acc[nn] = fmaf(vv.y, wreg[r4 * 4 + 1], acc[nn]);
                acc[nn] = fmaf(vv.z, wreg[r4 * 4 + 2], acc[nn]);
                acc[nn] = fmaf(vv.w, wreg[r4 * 4 + 3], acc[nn]);
            }
        }
        __syncthreads();   // drains vmcnt (stage t+1 already landed) + barrier
        buf ^= 1;
    }
#undef STAGE

    // combine halves: h=1 deposits, h=0 adds and writes (pad 33: no conflict)
    float* red = (float*)tile;              // reuse LDS, 128*33 floats
    if (h == 1) {
#pragma unroll
        for (int nn = 0; nn < 32; ++nn) red[colt * 33 + nn] = acc[nn];
    }
    __syncthreads();
    if (h == 0) {
#pragma unroll
        for (int nn = 0; nn < 32; ++nn) {
            float sum = acc[nn] + red[colt * 33 + nn];
            outpart[(size_t)kc * 131072 + (size_t)nn * 4096 + cb * 128 + colt] = sum;
        }
    }
}

// ---- kernel 5: reduce 16 partials + bias, per-block sumsq -----------------
__global__ __launch_bounds__(256) void k_reduce(
    const float* __restrict__ outpart, const float* __restrict__ b2,
    float* __restrict__ out, float* __restrict__ ssp)
{
    const int i = (blockIdx.x * 256 + threadIdx.x) * 4;
    float4 o = make_float4(0.f, 0.f, 0.f, 0.f);
#pragma unroll
    for (int kc = 0; kc < 16; ++kc) {
        float4 t = *(const float4*)&outpart[(size_t)kc * 131072 + i];
        o.x += t.x; o.y += t.y; o.z += t.z; o.w += t.w;
    }
    float4 bb = *(const float4*)&b2[i & 4095];
    o.x += bb.x; o.y += bb.y; o.z += bb.z; o.w += bb.w;
    *(float4*)&out[i] = o;

    float ss = o.x * o.x + o.y * o.y + o.z * o.z + o.w * o.w;
#pragma unroll
    for (int off = 32; off > 0; off >>= 1) ss += __shfl_xor(ss, off, 64);
    __shared__ float lred[4];
    if ((threadIdx.x & 63) == 0) lred[threadIdx.x >> 6] = ss;
    __syncthreads();
    if (threadIdx.x == 0)
        ssp[blockIdx.x] = lred[0] + lred[1] + lred[2] + lred[3];
}

// ---- kernel 6: global L2 scale --------------------------------------------
__global__ __launch_bounds__(256) void k_scale(
    const float* __restrict__ ssp, float* __restrict__ out)
{
    float ss = 0.f;
#pragma unroll
    for (int t = 0; t < 128; ++t) ss += ssp[t];
    const float sc = rsqrtf(fmaxf(ss, EPSF));
    const int i = (blockIdx.x * 256 + threadIdx.x) * 4;
    float4 o = *(float4*)&out[i];
    o.x *= sc; o.y *= sc; o.z *= sc; o.w *= sc;
    *(float4*)&out[i] = o;
}

extern "C" void kernel_launch(void* const* d_in, const int* in_sizes, int n_in,
                              void* d_out, int out_size, void* d_ws, size_t ws_size,
                              hipStream_t stream)
{
    const float* x  = (const float*)d_in[0];
    const float* w1 = (const float*)d_in[1];
    const float* b1 = (const float*)d_in[2];
    const float* C  = (const float*)d_in[3];
    const float* w2 = (const float*)d_in[4];
    const float* b2 = (const float*)d_in[5];
    float* out = (float*)d_out;
    float* ws  = (float*)d_ws;

    // ws layout (floats) — peak 12.13 MiB (proven budget):
    //   s       [0,       2M)        phases 1-2
    //   v       [2M,      3M)        phases 2-3
    //   ap      [3M,      3M+32768)  phases 1-3
    //   ssp     [3M+32768, +128)     phases 5-6
    //   vn      [0,       1M)        phases 3-4 (over dead s)
    //   outpart [1M,      3M)        phases 4-5 (over dead s-top + v)
    float* s_buf   = ws;
    float* v_buf   = ws + 2097152;
    float* ap      = ws + 3145728;
    float* ssp     = ws + 3145728 + 32768;
    float* vn      = ws;
    float* outpart = ws + 1048576;

    k_assign<<<512, 256, 0, stream>>>(x, w1, b1, s_buf, ap);
    k_vlad  <<<512, 256, 0, stream>>>(s_buf, x, v_buf);
    k_norm  <<<512, 256, 0, stream>>>(v_buf, ap, C, vn);
    k_gemm2 <<<512, 256, 0, stream>>>(vn, w2, outpart);
    k_reduce<<<128, 256, 0, stream>>>(outpart, b2, out, ssp);
    k_scale <<<128, 256, 0, stream>>>(ssp, out);
}

// Round 6
// 431.388 us; speedup vs baseline: 2.2658x; 1.3988x over previous
//
#include <hip/hip_runtime.h>
#include <math.h>

#define EPSF 1e-12f
// N=32, HW=1024, D=512, K=64, OUT=4096, KD=32768

// ---- kernel 1: s = softmax(x @ W1 + b1); ap = per-block column sums -------
__global__ __launch_bounds__(256) void k_assign(
    const float* __restrict__ x, const float* __restrict__ w1,
    const float* __restrict__ b1, float* __restrict__ s,
    float* __restrict__ ap)
{
    const int tid   = threadIdx.x;
    const int lane  = tid & 63;
    const int h     = __builtin_amdgcn_readfirstlane(tid >> 6);  // 0..3
    const int pix0  = blockIdx.x * 64;
    const int kbase = h * 16;

    __shared__ float Xs[64][68];   // px x dd   (+pad)
    __shared__ float Ws[64][68];   // dd x k    (+pad)
    __shared__ float redm[4][64];
    __shared__ float reds[4][64];

    float acc[16];
#pragma unroll
    for (int i = 0; i < 16; ++i) acc[i] = b1[kbase + i];

    for (int c = 0; c < 8; ++c) {
        __syncthreads();
#pragma unroll
        for (int t = 0; t < 4; ++t) {          // stage x: 64px x 64dd
            int idx = tid + t * 256;
            int p   = idx >> 4;
            int d4  = (idx & 15) << 2;
            float4 xv = *(const float4*)&x[(size_t)(pix0 + p) * 512 + c * 64 + d4];
            *(float4*)&Xs[p][d4] = xv;
        }
#pragma unroll
        for (int t = 0; t < 4; ++t) {          // stage w1: 64dd x 64k
            int idx = tid + t * 256;
            int dd  = idx >> 4;
            int k4  = (idx & 15) << 2;
            float4 wv = *(const float4*)&w1[(size_t)(c * 64 + dd) * 64 + k4];
            *(float4*)&Ws[dd][k4] = wv;
        }
        __syncthreads();
#pragma unroll 2
        for (int dd4 = 0; dd4 < 16; ++dd4) {
            float4 xv = *(const float4*)&Xs[lane][dd4 * 4];
#pragma unroll
            for (int ddl = 0; ddl < 4; ++ddl) {
                const float xs = (ddl == 0) ? xv.x : (ddl == 1) ? xv.y :
                                 (ddl == 2) ? xv.z : xv.w;
#pragma unroll
                for (int kk4 = 0; kk4 < 4; ++kk4) {
                    float4 wv = *(const float4*)&Ws[dd4 * 4 + ddl][kbase + kk4 * 4];
                    acc[kk4 * 4 + 0] = fmaf(xs, wv.x, acc[kk4 * 4 + 0]);
                    acc[kk4 * 4 + 1] = fmaf(xs, wv.y, acc[kk4 * 4 + 1]);
                    acc[kk4 * 4 + 2] = fmaf(xs, wv.z, acc[kk4 * 4 + 2]);
                    acc[kk4 * 4 + 3] = fmaf(xs, wv.w, acc[kk4 * 4 + 3]);
                }
            }
        }
    }

    float m = acc[0];
#pragma unroll
    for (int i = 1; i < 16; ++i) m = fmaxf(m, acc[i]);
    redm[h][lane] = m;
    __syncthreads();
    m = fmaxf(fmaxf(redm[0][lane], redm[1][lane]),
              fmaxf(redm[2][lane], redm[3][lane]));
    float sum = 0.f;
#pragma unroll
    for (int i = 0; i < 16; ++i) { acc[i] = __expf(acc[i] - m); sum += acc[i]; }
    reds[h][lane] = sum;
    __syncthreads();
    const float inv = 1.0f / (reds[0][lane] + reds[1][lane] +
                              reds[2][lane] + reds[3][lane]);
#pragma unroll
    for (int i = 0; i < 16; ++i) acc[i] *= inv;

    float* srow = s + (size_t)(pix0 + lane) * 64 + kbase;
#pragma unroll
    for (int i = 0; i < 16; i += 4)
        *(float4*)(srow + i) = make_float4(acc[i], acc[i+1], acc[i+2], acc[i+3]);

#pragma unroll
    for (int i = 0; i < 16; ++i) {
        float v = acc[i];
#pragma unroll
        for (int off = 32; off > 0; off >>= 1) v += __shfl_xor(v, off, 64);
        if (lane == 0) ap[(size_t)blockIdx.x * 64 + kbase + i] = v;
    }
}

// ---- kernel 2: v[n,k,d] = sum_p s[p,k] * x[p,d] ---------------------------
__global__ __launch_bounds__(256) void k_vlad(
    const float* __restrict__ s, const float* __restrict__ x,
    float* __restrict__ v)
{
    const int b  = blockIdx.x;
    const int n  = b >> 4;
    const int kh = (b >> 3) & 1;
    const int dc = b & 7;
    const int kt = threadIdx.x >> 4;       // 0..15
    const int dt = threadIdx.x & 15;       // 0..15
    const int k0 = kh * 32 + kt * 2;
    const int d0 = dc * 64 + dt * 4;
    const int pixbase = n * 1024;

    float4 a0 = make_float4(0.f, 0.f, 0.f, 0.f);
    float4 a1 = make_float4(0.f, 0.f, 0.f, 0.f);
    const float* xp = x + (size_t)pixbase * 512 + d0;
    const float* sp = s + (size_t)pixbase * 64 + k0;
#pragma unroll 4
    for (int p = 0; p < 1024; ++p) {
        float4 xv = *(const float4*)(xp + (size_t)p * 512);
        float2 sv = *(const float2*)(sp + (size_t)p * 64);
        a0.x = fmaf(sv.x, xv.x, a0.x); a0.y = fmaf(sv.x, xv.y, a0.y);
        a0.z = fmaf(sv.x, xv.z, a0.z); a0.w = fmaf(sv.x, xv.w, a0.w);
        a1.x = fmaf(sv.y, xv.x, a1.x); a1.y = fmaf(sv.y, xv.y, a1.y);
        a1.z = fmaf(sv.y, xv.z, a1.z); a1.w = fmaf(sv.y, xv.w, a1.w);
    }
    float* vp = v + ((size_t)(n * 64 + k0)) * 512 + d0;
    *(float4*)vp         = a0;
    *(float4*)(vp + 512) = a1;
}

// ---- kernel 3: vn = intra-L2-norm(v + a*C) * 1/8 --------------------------
__global__ __launch_bounds__(256) void k_norm(
    const float* __restrict__ v, const float* __restrict__ ap,
    const float* __restrict__ C, float* __restrict__ vn)
{
    const int lane = threadIdx.x & 63;
    const int w    = threadIdx.x >> 6;
    const int row  = blockIdx.x * 4 + w;   // n*64 + k
    const int n    = row >> 6;
    const int k    = row & 63;

    float a_nk = 0.f;
#pragma unroll
    for (int t = 0; t < 16; ++t)
        a_nk += ap[((size_t)(n * 16 + t)) * 64 + k];

    const float* vr = v + (size_t)row * 512;
    float vv[8];
    float ss = 0.f;
#pragma unroll
    for (int j = 0; j < 8; ++j) {
        int d = j * 64 + lane;
        float t = vr[d] + a_nk * C[(size_t)d * 64 + k];
        vv[j] = t;
        ss = fmaf(t, t, ss);
    }
#pragma unroll
    for (int off = 32; off > 0; off >>= 1) ss += __shfl_xor(ss, off, 64);
    const float scale = rsqrtf(fmaxf(ss, EPSF)) * 0.125f;
    float* vo = vn + (size_t)row * 512;
#pragma unroll
    for (int j = 0; j < 8; ++j) vo[j * 64 + lane] = vv[j] * scale;
}

// ---- kernel 4: outpart[kc] = vn @ W2 slice --------------------------------
// grid 512 = kc(16) x cb(32); block 128 thr (2 waves). Wave w owns n-range
// [w*16, +16) -> NO cross-wave reduce. Thread = 2 cols x 16 n (acc 32 VGPR).
// Per 32-row K-tile, BOTH operands staged to LDS via global_load_lds:
//   Bs[32][128] (16 KB) -- w2 stream;  As[32n][32k] (4 KB) -- vn slice.
// Round-5 read vn via s_load (scalar cache): 256 loads/tile vs ~10 in
// flight under the ~102-SGPR cap -> latency-bound (VALU 13%, HBM 9%).
// LDS broadcast reads (uniform addr = conflict-free) are throughput-pipe.
// Per wave per tile: 32 ds_read_b64 (B->regs, 2-way=free) +
// 128 uniform ds_read_b128 (A) + 1024 FMA. 40 KB LDS -> 4 blocks/CU,
// 80 KB HBM in flight/CU >> Little's law.
__global__ __launch_bounds__(128, 2) void k_gemm2(
    const float* __restrict__ vn, const float* __restrict__ w2,
    float* __restrict__ outpart)
{
    __shared__ float Bs[2][32][128];   // 32 KB
    __shared__ float As[2][32][32];    //  8 KB  [n][k]

    const int tid  = threadIdx.x;
    const int lane = tid & 63;
    const int w    = __builtin_amdgcn_readfirstlane(tid >> 6);  // 0/1
    const int kc   = blockIdx.x >> 5;
    const int cb   = blockIdx.x & 31;
    const int rowbase = kc * 2048;
    const int colbase = cb * 128;
    const int woff = w * 16;

    float2 acc[16];
#pragma unroll
    for (int n = 0; n < 16; ++n) acc[n] = make_float2(0.f, 0.f);

    // B: 16 instr/block (8/wave), each 1 KB: instr g covers rows g*2,g*2+1.
    // A: 4 instr (wave 0), each covers 8 n-rows of 32 k.
    // LDS dests are linear (base + lane*16) -- verified against src layout.
#define STAGE(T_, B_)                                                         \
    do {                                                                      \
        const int r0_ = rowbase + (T_) * 32;                                  \
        _Pragma("unroll")                                                     \
        for (int i_ = 0; i_ < 8; ++i_) {                                      \
            const int g_ = w * 8 + i_;                                        \
            const int k_ = g_ * 2 + (lane >> 5);                              \
            __builtin_amdgcn_global_load_lds(                                 \
                (const __attribute__((address_space(1))) void*)               \
                    (w2 + (size_t)(r0_ + k_) * 4096 + colbase + (lane & 31) * 4), \
                (__attribute__((address_space(3))) void*)&Bs[B_][g_ * 2][0],  \
                16, 0, 0);                                                    \
        }                                                                     \
        if (w == 0) {                                                         \
            _Pragma("unroll")                                                 \
            for (int i_ = 0; i_ < 4; ++i_) {                                  \
                const int n_  = i_ * 8 + (lane >> 3);                         \
                const int k4_ = lane & 7;                                     \
                __builtin_amdgcn_global_load_lds(                             \
                    (const __attribute__((address_space(1))) void*)           \
                        (vn + (size_t)n_ * 32768 + r0_ + k4_ * 4),            \
                    (__attribute__((address_space(3))) void*)&As[B_][i_ * 8][0], \
                    16, 0, 0);                                                \
            }                                                                 \
        }                                                                     \
    } while (0)

    STAGE(0, 0);
    __syncthreads();

    int buf = 0;
    for (int t = 0; t < 64; ++t) {
        if (t + 1 < 64) STAGE(t + 1, buf ^ 1);

        // B columns for this thread: cols lane*2, lane*2+1
        float2 b[32];
#pragma unroll
        for (int k = 0; k < 32; ++k)
            b[k] = *(const float2*)&Bs[buf][k][lane * 2];

#pragma unroll
        for (int n = 0; n < 16; ++n) {
#pragma unroll
            for (int k4 = 0; k4 < 8; ++k4) {
                float4 av = *(const float4*)&As[buf][woff + n][k4 * 4]; // bcast
                acc[n].x = fmaf(av.x, b[k4 * 4 + 0].x, acc[n].x);
                acc[n].y = fmaf(av.x, b[k4 * 4 + 0].y, acc[n].y);
                acc[n].x = fmaf(av.y, b[k4 * 4 + 1].x, acc[n].x);
                acc[n].y = fmaf(av.y, b[k4 * 4 + 1].y, acc[n].y);
                acc[n].x = fmaf(av.z, b[k4 * 4 + 2].x, acc[n].x);
                acc[n].y = fmaf(av.z, b[k4 * 4 + 2].y, acc[n].y);
                acc[n].x = fmaf(av.w, b[k4 * 4 + 3].x, acc[n].x);
                acc[n].y = fmaf(av.w, b[k4 * 4 + 3].y, acc[n].y);
            }
        }
        __syncthreads();   // drains vmcnt (stage t+1 landed) + barrier
        buf ^= 1;
    }
#undef STAGE

#pragma unroll
    for (int n = 0; n < 16; ++n)
        *(float2*)&outpart[(size_t)kc * 131072 + (size_t)(woff + n) * 4096 +
                           colbase + lane * 2] = acc[n];
}

// ---- kernel 5: reduce 16 partials + bias, per-block sumsq -----------------
__global__ __launch_bounds__(256) void k_reduce(
    const float* __restrict__ outpart, const float* __restrict__ b2,
    float* __restrict__ out, float* __restrict__ ssp)
{
    const int i = (blockIdx.x * 256 + threadIdx.x) * 4;
    float4 o = make_float4(0.f, 0.f, 0.f, 0.f);
#pragma unroll
    for (int kc = 0; kc < 16; ++kc) {
        float4 t = *(const float4*)&outpart[(size_t)kc * 131072 + i];
        o.x += t.x; o.y += t.y; o.z += t.z; o.w += t.w;
    }
    float4 bb = *(const float4*)&b2[i & 4095];
    o.x += bb.x; o.y += bb.y; o.z += bb.z; o.w += bb.w;
    *(float4*)&out[i] = o;

    float ss = o.x * o.x + o.y * o.y + o.z * o.z + o.w * o.w;
#pragma unroll
    for (int off = 32; off > 0; off >>= 1) ss += __shfl_xor(ss, off, 64);
    __shared__ float lred[4];
    if ((threadIdx.x & 63) == 0) lred[threadIdx.x >> 6] = ss;
    __syncthreads();
    if (threadIdx.x == 0)
        ssp[blockIdx.x] = lred[0] + lred[1] + lred[2] + lred[3];
}

// ---- kernel 6: global L2 scale --------------------------------------------
__global__ __launch_bounds__(256) void k_scale(
    const float* __restrict__ ssp, float* __restrict__ out)
{
    float ss = 0.f;
#pragma unroll
    for (int t = 0; t < 128; ++t) ss += ssp[t];
    const float sc = rsqrtf(fmaxf(ss, EPSF));
    const int i = (blockIdx.x * 256 + threadIdx.x) * 4;
    float4 o = *(float4*)&out[i];
    o.x *= sc; o.y *= sc; o.z *= sc; o.w *= sc;
    *(float4*)&out[i] = o;
}

extern "C" void kernel_launch(void* const* d_in, const int* in_sizes, int n_in,
                              void* d_out, int out_size, void* d_ws, size_t ws_size,
                              hipStream_t stream)
{
    const float* x  = (const float*)d_in[0];
    const float* w1 = (const float*)d_in[1];
    const float* b1 = (const float*)d_in[2];
    const float* C  = (const float*)d_in[3];
    const float* w2 = (const float*)d_in[4];
    const float* b2 = (const float*)d_in[5];
    float* out = (float*)d_out;
    float* ws  = (float*)d_ws;

    // ws layout (floats) — peak 12.13 MiB (proven budget):
    //   s       [0,       2M)        phases 1-2
    //   v       [2M,      3M)        phases 2-3
    //   ap      [3M,      3M+32768)  phases 1-3
    //   ssp     [3M+32768, +128)     phases 5-6
    //   vn      [0,       1M)        phases 3-4 (over dead s)
    //   outpart [1M,      3M)        phases 4-5 (over dead s-top + v)
    float* s_buf   = ws;
    float* v_buf   = ws + 2097152;
    float* ap      = ws + 3145728;
    float* ssp     = ws + 3145728 + 32768;
    float* vn      = ws;
    float* outpart = ws + 1048576;

    k_assign<<<512, 256, 0, stream>>>(x, w1, b1, s_buf, ap);
    k_vlad  <<<512, 256, 0, stream>>>(s_buf, x, v_buf);
    k_norm  <<<512, 256, 0, stream>>>(v_buf, ap, C, vn);
    k_gemm2 <<<512, 128, 0, stream>>>(vn, w2, outpart);
    k_reduce<<<128, 256, 0, stream>>>(outpart, b2, out, ssp);
    k_scale <<<128, 256, 0, stream>>>(ssp, out);
}

// Round 7
// 274.131 us; speedup vs baseline: 3.5656x; 1.5737x over previous
//
#include <hip/hip_runtime.h>
#include <math.h>

#define EPSF 1e-12f
// N=32, HW=1024, D=512, K=64, OUT=4096, KD=32768

typedef __attribute__((ext_vector_type(8))) short short8v;  // 8 bf16
typedef __attribute__((ext_vector_type(4))) float f32x4;

__device__ __forceinline__ unsigned short f2bf(float f) {   // RNE
    unsigned int u = __float_as_uint(f);
    return (unsigned short)((u + 0x7FFF + ((u >> 16) & 1)) >> 16);
}

// ---- kernel 1: s = softmax(x @ W1 + b1); ap = per-block column sums -------
__global__ __launch_bounds__(256) void k_assign(
    const float* __restrict__ x, const float* __restrict__ w1,
    const float* __restrict__ b1, float* __restrict__ s,
    float* __restrict__ ap)
{
    const int tid   = threadIdx.x;
    const int lane  = tid & 63;
    const int h     = __builtin_amdgcn_readfirstlane(tid >> 6);  // 0..3
    const int pix0  = blockIdx.x * 64;
    const int kbase = h * 16;

    __shared__ float Xs[64][68];   // px x dd   (+pad)
    __shared__ float Ws[64][68];   // dd x k    (+pad)
    __shared__ float redm[4][64];
    __shared__ float reds[4][64];

    float acc[16];
#pragma unroll
    for (int i = 0; i < 16; ++i) acc[i] = b1[kbase + i];

    for (int c = 0; c < 8; ++c) {
        __syncthreads();
#pragma unroll
        for (int t = 0; t < 4; ++t) {          // stage x: 64px x 64dd
            int idx = tid + t * 256;
            int p   = idx >> 4;
            int d4  = (idx & 15) << 2;
            float4 xv = *(const float4*)&x[(size_t)(pix0 + p) * 512 + c * 64 + d4];
            *(float4*)&Xs[p][d4] = xv;
        }
#pragma unroll
        for (int t = 0; t < 4; ++t) {          // stage w1: 64dd x 64k
            int idx = tid + t * 256;
            int dd  = idx >> 4;
            int k4  = (idx & 15) << 2;
            float4 wv = *(const float4*)&w1[(size_t)(c * 64 + dd) * 64 + k4];
            *(float4*)&Ws[dd][k4] = wv;
        }
        __syncthreads();
#pragma unroll 2
        for (int dd4 = 0; dd4 < 16; ++dd4) {
            float4 xv = *(const float4*)&Xs[lane][dd4 * 4];
#pragma unroll
            for (int ddl = 0; ddl < 4; ++ddl) {
                const float xs = (ddl == 0) ? xv.x : (ddl == 1) ? xv.y :
                                 (ddl == 2) ? xv.z : xv.w;
#pragma unroll
                for (int kk4 = 0; kk4 < 4; ++kk4) {
                    float4 wv = *(const float4*)&Ws[dd4 * 4 + ddl][kbase + kk4 * 4];
                    acc[kk4 * 4 + 0] = fmaf(xs, wv.x, acc[kk4 * 4 + 0]);
                    acc[kk4 * 4 + 1] = fmaf(xs, wv.y, acc[kk4 * 4 + 1]);
                    acc[kk4 * 4 + 2] = fmaf(xs, wv.z, acc[kk4 * 4 + 2]);
                    acc[kk4 * 4 + 3] = fmaf(xs, wv.w, acc[kk4 * 4 + 3]);
                }
            }
        }
    }

    float m = acc[0];
#pragma unroll
    for (int i = 1; i < 16; ++i) m = fmaxf(m, acc[i]);
    redm[h][lane] = m;
    __syncthreads();
    m = fmaxf(fmaxf(redm[0][lane], redm[1][lane]),
              fmaxf(redm[2][lane], redm[3][lane]));
    float sum = 0.f;
#pragma unroll
    for (int i = 0; i < 16; ++i) { acc[i] = __expf(acc[i] - m); sum += acc[i]; }
    reds[h][lane] = sum;
    __syncthreads();
    const float inv = 1.0f / (reds[0][lane] + reds[1][lane] +
                              reds[2][lane] + reds[3][lane]);
#pragma unroll
    for (int i = 0; i < 16; ++i) acc[i] *= inv;

    float* srow = s + (size_t)(pix0 + lane) * 64 + kbase;
#pragma unroll
    for (int i = 0; i < 16; i += 4)
        *(float4*)(srow + i) = make_float4(acc[i], acc[i+1], acc[i+2], acc[i+3]);

#pragma unroll
    for (int i = 0; i < 16; ++i) {
        float v = acc[i];
#pragma unroll
        for (int off = 32; off > 0; off >>= 1) v += __shfl_xor(v, off, 64);
        if (lane == 0) ap[(size_t)blockIdx.x * 64 + kbase + i] = v;
    }
}

// ---- kernel 2: v[n,k,d] = sum_p s[p,k] * x[p,d] ---------------------------
__global__ __launch_bounds__(256) void k_vlad(
    const float* __restrict__ s, const float* __restrict__ x,
    float* __restrict__ v)
{
    const int b  = blockIdx.x;
    const int n  = b >> 4;
    const int kh = (b >> 3) & 1;
    const int dc = b & 7;
    const int kt = threadIdx.x >> 4;       // 0..15
    const int dt = threadIdx.x & 15;       // 0..15
    const int k0 = kh * 32 + kt * 2;
    const int d0 = dc * 64 + dt * 4;
    const int pixbase = n * 1024;

    float4 a0 = make_float4(0.f, 0.f, 0.f, 0.f);
    float4 a1 = make_float4(0.f, 0.f, 0.f, 0.f);
    const float* xp = x + (size_t)pixbase * 512 + d0;
    const float* sp = s + (size_t)pixbase * 64 + k0;
#pragma unroll 4
    for (int p = 0; p < 1024; ++p) {
        float4 xv = *(const float4*)(xp + (size_t)p * 512);
        float2 sv = *(const float2*)(sp + (size_t)p * 64);
        a0.x = fmaf(sv.x, xv.x, a0.x); a0.y = fmaf(sv.x, xv.y, a0.y);
        a0.z = fmaf(sv.x, xv.z, a0.z); a0.w = fmaf(sv.x, xv.w, a0.w);
        a1.x = fmaf(sv.y, xv.x, a1.x); a1.y = fmaf(sv.y, xv.y, a1.y);
        a1.z = fmaf(sv.y, xv.z, a1.z); a1.w = fmaf(sv.y, xv.w, a1.w);
    }
    float* vp = v + ((size_t)(n * 64 + k0)) * 512 + d0;
    *(float4*)vp         = a0;
    *(float4*)(vp + 512) = a1;
}

// ---- kernel 3: vn16 = bf16( intra-L2-norm(v + a*C) * 1/8 ) ----------------
// Same linear layout as before; bf16 output feeds the MFMA GEMM directly.
__global__ __launch_bounds__(256) void k_norm(
    const float* __restrict__ v, const float* __restrict__ ap,
    const float* __restrict__ C, unsigned short* __restrict__ vn16)
{
    const int lane = threadIdx.x & 63;
    const int w    = threadIdx.x >> 6;
    const int row  = blockIdx.x * 4 + w;   // n*64 + k
    const int n    = row >> 6;
    const int k    = row & 63;

    float a_nk = 0.f;
#pragma unroll
    for (int t = 0; t < 16; ++t)
        a_nk += ap[((size_t)(n * 16 + t)) * 64 + k];

    const float* vr = v + (size_t)row * 512;
    float vv[8];
    float ss = 0.f;
#pragma unroll
    for (int j = 0; j < 8; ++j) {
        int d = j * 64 + lane;
        float t = vr[d] + a_nk * C[(size_t)d * 64 + k];
        vv[j] = t;
        ss = fmaf(t, t, ss);
    }
#pragma unroll
    for (int off = 32; off > 0; off >>= 1) ss += __shfl_xor(ss, off, 64);
    const float scale = rsqrtf(fmaxf(ss, EPSF)) * 0.125f;
    unsigned short* vo = vn16 + (size_t)row * 512;
#pragma unroll
    for (int j = 0; j < 8; ++j) vo[j * 64 + lane] = f2bf(vv[j] * scale);
}

// ---- kernel 4: outpart[kc] = vn @ W2 slice (bf16 MFMA) --------------------
// grid 512 = kc(16) x cb(32); 256 thr (4 waves). Block = 32 m x 128 cols;
// wave wv owns cols [wv*32,+32) = 2 n-frags; m covered by 2 m-frags ->
// 4 MFMA (16x16x32 bf16) per wave-tile, acc 16 VGPR. w2 staged f32 via
// global_load_lds into dbuf Bs (32 KB -> 2 blocks/CU, 2 waves/SIMD),
// cvt'd to bf16 at consume (16 ds_read_b32 + 16 cvt per wave-tile vs
// r6's 160 DS instrs -> DS pipe no longer oversubscribed).
// A-frags (vn16, 2 MB, L2-hot) read direct from global: lanes l,l+16,
// l+32,l+48 cover one 64B line of row l&15.
// Fragment mapping: A/B lane&15 = m/n, k = 8*(lane>>4)+j;
// D col = lane&15, row = 4*(lane>>4)+reg (m89-verified).
__global__ __launch_bounds__(256, 2) void k_gemm2(
    const unsigned short* __restrict__ vn16, const float* __restrict__ w2,
    float* __restrict__ outpart)
{
    __shared__ float Bs[2][32][128];   // 32 KB double-buffered w2 tile

    const int tid  = threadIdx.x;
    const int lane = tid & 63;
    const int wv   = __builtin_amdgcn_readfirstlane(tid >> 6);  // 0..3
    const int kc   = blockIdx.x >> 5;
    const int cb   = blockIdx.x & 31;
    const int rowbase = kc * 2048;
    const int colbase = cb * 128;
    const int l4   = lane >> 4;        // 0..3 : k-group
    const int l16  = lane & 15;        // m / n within fragment

    f32x4 acc[2][2];
#pragma unroll
    for (int i = 0; i < 2; ++i)
#pragma unroll
        for (int j = 0; j < 2; ++j)
            acc[i][j] = (f32x4){0.f, 0.f, 0.f, 0.f};

    // stage one 32-row x 128-col f32 tile; LDS dest linear (row-major),
    // matches global [k][n] layout. 4 instr/wave, 16/block, 1 KB each.
#define STAGE(T_, B_)                                                         \
    do {                                                                      \
        _Pragma("unroll")                                                     \
        for (int i_ = 0; i_ < 4; ++i_) {                                      \
            const int r_ = (wv * 4 + i_) * 2 + (lane >> 5);                   \
            __builtin_amdgcn_global_load_lds(                                 \
                (const __attribute__((address_space(1))) void*)               \
                    (w2 + (size_t)(rowbase + (T_) * 32 + r_) * 4096 +         \
                     colbase + (lane & 31) * 4),                              \
                (__attribute__((address_space(3))) void*)                     \
                    &Bs[B_][(wv * 4 + i_) * 2][0],                            \
                16, 0, 0);                                                    \
        }                                                                     \
    } while (0)

    STAGE(0, 0);
    __syncthreads();

    int buf = 0;
    for (int t = 0; t < 64; ++t) {
        if (t + 1 < 64) STAGE(t + 1, buf ^ 1);

        // A fragments: vn16[m][rowbase + t*32 + l4*8 .. +8]
        const unsigned short* va = vn16 + (size_t)(rowbase + t * 32 + l4 * 8);
        short8v a0 = *(const short8v*)(va + (size_t)l16 * 32768);
        short8v a1 = *(const short8v*)(va + (size_t)(16 + l16) * 32768);

#pragma unroll
        for (int nf = 0; nf < 2; ++nf) {
            const int cl = wv * 32 + nf * 16 + l16;
            short8v bfr;
#pragma unroll
            for (int j = 0; j < 8; ++j)
                bfr[j] = (short)f2bf(Bs[buf][l4 * 8 + j][cl]);
            acc[0][nf] = __builtin_amdgcn_mfma_f32_16x16x32_bf16(
                a0, bfr, acc[0][nf], 0, 0, 0);
            acc[1][nf] = __builtin_amdgcn_mfma_f32_16x16x32_bf16(
                a1, bfr, acc[1][nf], 0, 0, 0);
        }
        __syncthreads();   // drains vmcnt (stage t+1 landed) + barrier
        buf ^= 1;
    }
#undef STAGE

    // D: col = lane&15, row = 4*(lane>>4)+reg
#pragma unroll
    for (int mf = 0; mf < 2; ++mf)
#pragma unroll
        for (int nf = 0; nf < 2; ++nf)
#pragma unroll
            for (int r = 0; r < 4; ++r) {
                const int m  = mf * 16 + l4 * 4 + r;
                const int cl = colbase + wv * 32 + nf * 16 + l16;
                outpart[(size_t)kc * 131072 + (size_t)m * 4096 + cl] =
                    acc[mf][nf][r];
            }
}

// ---- kernel 5: reduce 16 partials + bias, per-block sumsq -----------------
__global__ __launch_bounds__(256) void k_reduce(
    const float* __restrict__ outpart, const float* __restrict__ b2,
    float* __restrict__ out, float* __restrict__ ssp)
{
    const int i = (blockIdx.x * 256 + threadIdx.x) * 4;
    float4 o = make_float4(0.f, 0.f, 0.f, 0.f);
#pragma unroll
    for (int kc = 0; kc < 16; ++kc) {
        float4 t = *(const float4*)&outpart[(size_t)kc * 131072 + i];
        o.x += t.x; o.y += t.y; o.z += t.z; o.w += t.w;
    }
    float4 bb = *(const float4*)&b2[i & 4095];
    o.x += bb.x; o.y += bb.y; o.z += bb.z; o.w += bb.w;
    *(float4*)&out[i] = o;

    float ss = o.x * o.x + o.y * o.y + o.z * o.z + o.w * o.w;
#pragma unroll
    for (int off = 32; off > 0; off >>= 1) ss += __shfl_xor(ss, off, 64);
    __shared__ float lred[4];
    if ((threadIdx.x & 63) == 0) lred[threadIdx.x >> 6] = ss;
    __syncthreads();
    if (threadIdx.x == 0)
        ssp[blockIdx.x] = lred[0] + lred[1] + lred[2] + lred[3];
}

// ---- kernel 6: global L2 scale --------------------------------------------
__global__ __launch_bounds__(256) void k_scale(
    const float* __restrict__ ssp, float* __restrict__ out)
{
    float ss = 0.f;
#pragma unroll
    for (int t = 0; t < 128; ++t) ss += ssp[t];
    const float sc = rsqrtf(fmaxf(ss, EPSF));
    const int i = (blockIdx.x * 256 + threadIdx.x) * 4;
    float4 o = *(float4*)&out[i];
    o.x *= sc; o.y *= sc; o.z *= sc; o.w *= sc;
    *(float4*)&out[i] = o;
}

extern "C" void kernel_launch(void* const* d_in, const int* in_sizes, int n_in,
                              void* d_out, int out_size, void* d_ws, size_t ws_size,
                              hipStream_t stream)
{
    const float* x  = (const float*)d_in[0];
    const float* w1 = (const float*)d_in[1];
    const float* b1 = (const float*)d_in[2];
    const float* C  = (const float*)d_in[3];
    const float* w2 = (const float*)d_in[4];
    const float* b2 = (const float*)d_in[5];
    float* out = (float*)d_out;
    float* ws  = (float*)d_ws;

    // ws layout (floats) — peak 12.0 MiB (proven budget):
    //   s       [0,       2M)        phases 1-2
    //   v       [2M,      3M)        phases 2-3
    //   ap      [3M,      3M+32768)  phases 1-3
    //   ssp     [3M+32768, +128)     phases 5-6
    //   vn16    [0,       0.5M)      phases 3-4 (bf16 in dead s; 2 MB)
    //   outpart [1M,      3M)        phases 4-5 (over dead s-top + v)
    float* s_buf   = ws;
    float* v_buf   = ws + 2097152;
    float* ap      = ws + 3145728;
    float* ssp     = ws + 3145728 + 32768;
    unsigned short* vn16 = (unsigned short*)ws;
    float* outpart = ws + 1048576;

    k_assign<<<512, 256, 0, stream>>>(x, w1, b1, s_buf, ap);
    k_vlad  <<<512, 256, 0, stream>>>(s_buf, x, v_buf);
    k_norm  <<<512, 256, 0, stream>>>(v_buf, ap, C, vn16);
    k_gemm2 <<<512, 256, 0, stream>>>(vn16, w2, outpart);
    k_reduce<<<128, 256, 0, stream>>>(outpart, b2, out, ssp);
    k_scale <<<128, 256, 0, stream>>>(ssp, out);
}

// Round 10
// 271.623 us; speedup vs baseline: 3.5985x; 1.0092x over previous
//
#include <hip/hip_runtime.h>
#include <math.h>

#define EPSF 1e-12f
// N=32, HW=1024, D=512, K=64, OUT=4096, KD=32768

typedef __attribute__((ext_vector_type(8))) short short8v;  // 8 bf16
typedef __attribute__((ext_vector_type(4))) float f32x4;

__device__ __forceinline__ unsigned short f2bf(float f) {   // RNE
    unsigned int u = __float_as_uint(f);
    return (unsigned short)((u + 0x7FFF + ((u >> 16) & 1)) >> 16);
}
__device__ __forceinline__ float bf2f(unsigned short h) {
    return __uint_as_float(((unsigned int)h) << 16);
}

// ---- kernel 0: w1 [512 d][64 k] f32 -> w1t hi/lo bf16 [64 k][512 d] -------
__global__ __launch_bounds__(256) void k_prep(
    const float* __restrict__ w1,
    unsigned short* __restrict__ w1t_h, unsigned short* __restrict__ w1t_l)
{
    const int i  = blockIdx.x * 256 + threadIdx.x;   // 0..8191
    const int k  = i >> 7;
    const int d0 = (i & 127) << 2;
    float vv[4];
#pragma unroll
    for (int j = 0; j < 4; ++j) vv[j] = w1[(size_t)(d0 + j) * 64 + k];
    ushort4 h, l;
    h.x = f2bf(vv[0]); l.x = f2bf(vv[0] - bf2f(h.x));
    h.y = f2bf(vv[1]); l.y = f2bf(vv[1] - bf2f(h.y));
    h.z = f2bf(vv[2]); l.z = f2bf(vv[2] - bf2f(h.z));
    h.w = f2bf(vv[3]); l.w = f2bf(vv[3] - bf2f(h.w));
    *(ushort4*)(w1t_h + (size_t)k * 512 + d0) = h;
    *(ushort4*)(w1t_l + (size_t)k * 512 + d0) = l;
}

// ---- kernel 1: logits = x @ W1 (split-bf16 MFMA) -> LDS -> r5-proven ------
// softmax/store epilogue. r9 structure unchanged; r8/r9 failures were the
// w1t_h/w1t_l ALLOCATION OVERLAP (w1t_h = 32768 shorts = 16384 floats, but
// l was placed +8192 floats -> w1t_l[k][d] aliased w1t_h[k+32][d], racing
// across blocks). Fixed in the launcher only.
__global__ __launch_bounds__(256) void k_assign(
    const float* __restrict__ x,
    const unsigned short* __restrict__ w1t_h,
    const unsigned short* __restrict__ w1t_l,
    const float* __restrict__ b1,
    float* __restrict__ s, float* __restrict__ ap)
{
    const int tid  = threadIdx.x;
    const int lane = tid & 63;
    const int wv   = __builtin_amdgcn_readfirstlane(tid >> 6);  // 0..3
    const int l4   = lane >> 4;
    const int l16  = lane & 15;
    const int pix0 = blockIdx.x * 64;

    __shared__ unsigned short Xh[64][72];   // +8 pad: conflict-free b128
    __shared__ unsigned short Xl[64][72];
    __shared__ float Ls[64][65];            // logits [px][k]
    __shared__ float redm[4][64];
    __shared__ float reds[4][64];

    f32x4 acc[4];
#pragma unroll
    for (int nf = 0; nf < 4; ++nf) acc[nf] = (f32x4){0.f, 0.f, 0.f, 0.f};

    float4 xr[4];
#pragma unroll
    for (int t = 0; t < 4; ++t) {            // prologue: chunk 0 -> regs
        int idx = tid + t * 256, p = idx >> 4, d4 = (idx & 15) << 2;
        xr[t] = *(const float4*)&x[(size_t)(pix0 + p) * 512 + d4];
    }

    for (int c = 0; c < 8; ++c) {
        __syncthreads();                     // prev chunk's LDS reads done
#pragma unroll
        for (int t = 0; t < 4; ++t) {        // cvt + write LDS (split pair)
            int idx = tid + t * 256, p = idx >> 4, d4 = (idx & 15) << 2;
            float4 v = xr[t];
            ushort4 h4, l4v;
            h4.x = f2bf(v.x); l4v.x = f2bf(v.x - bf2f(h4.x));
            h4.y = f2bf(v.y); l4v.y = f2bf(v.y - bf2f(h4.y));
            h4.z = f2bf(v.z); l4v.z = f2bf(v.z - bf2f(h4.z));
            h4.w = f2bf(v.w); l4v.w = f2bf(v.w - bf2f(h4.w));
            *(ushort4*)&Xh[p][d4] = h4;
            *(ushort4*)&Xl[p][d4] = l4v;
        }
        if (c + 1 < 8) {                     // prefetch next chunk
#pragma unroll
            for (int t = 0; t < 4; ++t) {
                int idx = tid + t * 256, p = idx >> 4, d4 = (idx & 15) << 2;
                xr[t] = *(const float4*)&x[(size_t)(pix0 + p) * 512 +
                                           (c + 1) * 64 + d4];
            }
        }
        __syncthreads();
#pragma unroll
        for (int ks = 0; ks < 2; ++ks) {     // 2 k-steps of 32 d
            short8v ah = *(const short8v*)&Xh[wv * 16 + l16][ks * 32 + l4 * 8];
            short8v al = *(const short8v*)&Xl[wv * 16 + l16][ks * 32 + l4 * 8];
#pragma unroll
            for (int nf = 0; nf < 4; ++nf) {
                const size_t wo = (size_t)(nf * 16 + l16) * 512 +
                                  c * 64 + ks * 32 + l4 * 8;
                short8v bh = *(const short8v*)(w1t_h + wo);
                short8v bl = *(const short8v*)(w1t_l + wo);
                acc[nf] = __builtin_amdgcn_mfma_f32_16x16x32_bf16(ah, bh, acc[nf], 0, 0, 0);
                acc[nf] = __builtin_amdgcn_mfma_f32_16x16x32_bf16(ah, bl, acc[nf], 0, 0, 0);
                acc[nf] = __builtin_amdgcn_mfma_f32_16x16x32_bf16(al, bh, acc[nf], 0, 0, 0);
            }
        }
    }

    // logits -> LDS via r7-validated D-mapping: row=4*l4+r -> px-in-tile,
    // col=l16 -> k-in-fragment
    __syncthreads();
#pragma unroll
    for (int nf = 0; nf < 4; ++nf)
#pragma unroll
        for (int r = 0; r < 4; ++r)
            Ls[wv * 16 + l4 * 4 + r][nf * 16 + l16] = acc[nf][r];
    __syncthreads();

    // ---- r5-proven epilogue: lane = px, wave wv owns k-range [wv*16,+16) --
    const int kbase = wv * 16;
    float sacc[16];
#pragma unroll
    for (int i = 0; i < 16; ++i) sacc[i] = Ls[lane][kbase + i] + b1[kbase + i];

    float m = sacc[0];
#pragma unroll
    for (int i = 1; i < 16; ++i) m = fmaxf(m, sacc[i]);
    redm[wv][lane] = m;
    __syncthreads();
    m = fmaxf(fmaxf(redm[0][lane], redm[1][lane]),
              fmaxf(redm[2][lane], redm[3][lane]));
    float sum = 0.f;
#pragma unroll
    for (int i = 0; i < 16; ++i) { sacc[i] = __expf(sacc[i] - m); sum += sacc[i]; }
    reds[wv][lane] = sum;
    __syncthreads();
    const float inv = 1.0f / (reds[0][lane] + reds[1][lane] +
                              reds[2][lane] + reds[3][lane]);
#pragma unroll
    for (int i = 0; i < 16; ++i) sacc[i] *= inv;

    float* srow = s + (size_t)(pix0 + lane) * 64 + kbase;
#pragma unroll
    for (int i = 0; i < 16; i += 4)
        *(float4*)(srow + i) = make_float4(sacc[i], sacc[i+1], sacc[i+2], sacc[i+3]);

#pragma unroll
    for (int i = 0; i < 16; ++i) {
        float v = sacc[i];
#pragma unroll
        for (int off = 32; off > 0; off >>= 1) v += __shfl_xor(v, off, 64);
        if (lane == 0) ap[(size_t)blockIdx.x * 64 + kbase + i] = v;
    }
}

// ---- kernel 2: v[n,k,d] = sum_p s[p,k] * x[p,d]  (r7-proven, f32) ---------
__global__ __launch_bounds__(256) void k_vlad(
    const float* __restrict__ s, const float* __restrict__ x,
    float* __restrict__ v)
{
    const int b  = blockIdx.x;
    const int n  = b >> 4;
    const int kh = (b >> 3) & 1;
    const int dc = b & 7;
    const int kt = threadIdx.x >> 4;       // 0..15
    const int dt = threadIdx.x & 15;       // 0..15
    const int k0 = kh * 32 + kt * 2;
    const int d0 = dc * 64 + dt * 4;
    const int pixbase = n * 1024;

    float4 a0 = make_float4(0.f, 0.f, 0.f, 0.f);
    float4 a1 = make_float4(0.f, 0.f, 0.f, 0.f);
    const float* xp = x + (size_t)pixbase * 512 + d0;
    const float* sp = s + (size_t)pixbase * 64 + k0;
#pragma unroll 4
    for (int p = 0; p < 1024; ++p) {
        float4 xv = *(const float4*)(xp + (size_t)p * 512);
        float2 sv = *(const float2*)(sp + (size_t)p * 64);
        a0.x = fmaf(sv.x, xv.x, a0.x); a0.y = fmaf(sv.x, xv.y, a0.y);
        a0.z = fmaf(sv.x, xv.z, a0.z); a0.w = fmaf(sv.x, xv.w, a0.w);
        a1.x = fmaf(sv.y, xv.x, a1.x); a1.y = fmaf(sv.y, xv.y, a1.y);
        a1.z = fmaf(sv.y, xv.z, a1.z); a1.w = fmaf(sv.y, xv.w, a1.w);
    }
    float* vp = v + ((size_t)(n * 64 + k0)) * 512 + d0;
    *(float4*)vp         = a0;
    *(float4*)(vp + 512) = a1;
}

// ---- kernel 3: vn16 = bf16( intra-L2-norm(v + a*C) * 1/8 )  (r7-proven) ---
__global__ __launch_bounds__(256) void k_norm(
    const float* __restrict__ v, const float* __restrict__ ap,
    const float* __restrict__ C, unsigned short* __restrict__ vn16)
{
    const int lane = threadIdx.x & 63;
    const int w    = threadIdx.x >> 6;
    const int row  = blockIdx.x * 4 + w;   // n*64 + k
    const int n    = row >> 6;
    const int k    = row & 63;

    float a_nk = 0.f;
#pragma unroll
    for (int t = 0; t < 16; ++t)
        a_nk += ap[((size_t)(n * 16 + t)) * 64 + k];

    const float* vr = v + (size_t)row * 512;
    float vv[8];
    float ss = 0.f;
#pragma unroll
    for (int j = 0; j < 8; ++j) {
        int d = j * 64 + lane;
        float t = vr[d] + a_nk * C[(size_t)d * 64 + k];
        vv[j] = t;
        ss = fmaf(t, t, ss);
    }
#pragma unroll
    for (int off = 32; off > 0; off >>= 1) ss += __shfl_xor(ss, off, 64);
    const float scale = rsqrtf(fmaxf(ss, EPSF)) * 0.125f;
    unsigned short* vo = vn16 + (size_t)row * 512;
#pragma unroll
    for (int j = 0; j < 8; ++j) vo[j * 64 + lane] = f2bf(vv[j] * scale);
}

// ---- kernel 4: outpart[kc] = vn @ W2 slice (bf16 MFMA)  (r7-proven) -------
__global__ __launch_bounds__(256, 2) void k_gemm2(
    const unsigned short* __restrict__ vn16, const float* __restrict__ w2,
    float* __restrict__ outpart)
{
    __shared__ float Bs[2][32][128];   // 32 KB double-buffered w2 tile

    const int tid  = threadIdx.x;
    const int lane = tid & 63;
    const int wv   = __builtin_amdgcn_readfirstlane(tid >> 6);  // 0..3
    const int kc   = blockIdx.x >> 5;
    const int cb   = blockIdx.x & 31;
    const int rowbase = kc * 2048;
    const int colbase = cb * 128;
    const int l4   = lane >> 4;
    const int l16  = lane & 15;

    f32x4 acc[2][2];
#pragma unroll
    for (int i = 0; i < 2; ++i)
#pragma unroll
        for (int j = 0; j < 2; ++j)
            acc[i][j] = (f32x4){0.f, 0.f, 0.f, 0.f};

#define STAGE(T_, B_)                                                         \
    do {                                                                      \
        _Pragma("unroll")                                                     \
        for (int i_ = 0; i_ < 4; ++i_) {                                      \
            const int r_ = (wv * 4 + i_) * 2 + (lane >> 5);                   \
            __builtin_amdgcn_global_load_lds(                                 \
                (const __attribute__((address_space(1))) void*)               \
                    (w2 + (size_t)(rowbase + (T_) * 32 + r_) * 4096 +         \
                     colbase + (lane & 31) * 4),                              \
                (__attribute__((address_space(3))) void*)                     \
                    &Bs[B_][(wv * 4 + i_) * 2][0],                            \
                16, 0, 0);                                                    \
        }                                                                     \
    } while (0)

    STAGE(0, 0);
    __syncthreads();

    int buf = 0;
    for (int t = 0; t < 64; ++t) {
        if (t + 1 < 64) STAGE(t + 1, buf ^ 1);

        const unsigned short* va = vn16 + (size_t)(rowbase + t * 32 + l4 * 8);
        short8v a0 = *(const short8v*)(va + (size_t)l16 * 32768);
        short8v a1 = *(const short8v*)(va + (size_t)(16 + l16) * 32768);

#pragma unroll
        for (int nf = 0; nf < 2; ++nf) {
            const int cl = wv * 32 + nf * 16 + l16;
            short8v bfr;
#pragma unroll
            for (int j = 0; j < 8; ++j)
                bfr[j] = (short)f2bf(Bs[buf][l4 * 8 + j][cl]);
            acc[0][nf] = __builtin_amdgcn_mfma_f32_16x16x32_bf16(
                a0, bfr, acc[0][nf], 0, 0, 0);
            acc[1][nf] = __builtin_amdgcn_mfma_f32_16x16x32_bf16(
                a1, bfr, acc[1][nf], 0, 0, 0);
        }
        __syncthreads();
        buf ^= 1;
    }
#undef STAGE

#pragma unroll
    for (int mf = 0; mf < 2; ++mf)
#pragma unroll
        for (int nf = 0; nf < 2; ++nf)
#pragma unroll
            for (int r = 0; r < 4; ++r) {
                const int m  = mf * 16 + l4 * 4 + r;
                const int cl = colbase + wv * 32 + nf * 16 + l16;
                outpart[(size_t)kc * 131072 + (size_t)m * 4096 + cl] =
                    acc[mf][nf][r];
            }
}

// ---- kernel 5: reduce 16 partials + bias, per-block sumsq -----------------
__global__ __launch_bounds__(256) void k_reduce(
    const float* __restrict__ outpart, const float* __restrict__ b2,
    float* __restrict__ out, float* __restrict__ ssp)
{
    const int i = (blockIdx.x * 256 + threadIdx.x) * 4;
    float4 o = make_float4(0.f, 0.f, 0.f, 0.f);
#pragma unroll
    for (int kc = 0; kc < 16; ++kc) {
        float4 t = *(const float4*)&outpart[(size_t)kc * 131072 + i];
        o.x += t.x; o.y += t.y; o.z += t.z; o.w += t.w;
    }
    float4 bb = *(const float4*)&b2[i & 4095];
    o.x += bb.x; o.y += bb.y; o.z += bb.z; o.w += bb.w;
    *(float4*)&out[i] = o;

    float ss = o.x * o.x + o.y * o.y + o.z * o.z + o.w * o.w;
#pragma unroll
    for (int off = 32; off > 0; off >>= 1) ss += __shfl_xor(ss, off, 64);
    __shared__ float lred[4];
    if ((threadIdx.x & 63) == 0) lred[threadIdx.x >> 6] = ss;
    __syncthreads();
    if (threadIdx.x == 0)
        ssp[blockIdx.x] = lred[0] + lred[1] + lred[2] + lred[3];
}

// ---- kernel 6: global L2 scale --------------------------------------------
__global__ __launch_bounds__(256) void k_scale(
    const float* __restrict__ ssp, float* __restrict__ out)
{
    float ss = 0.f;
#pragma unroll
    for (int t = 0; t < 128; ++t) ss += ssp[t];
    const float sc = rsqrtf(fmaxf(ss, EPSF));
    const int i = (blockIdx.x * 256 + threadIdx.x) * 4;
    float4 o = *(float4*)&out[i];
    o.x *= sc; o.y *= sc; o.z *= sc; o.w *= sc;
    *(float4*)&out[i] = o;
}

extern "C" void kernel_launch(void* const* d_in, const int* in_sizes, int n_in,
                              void* d_out, int out_size, void* d_ws, size_t ws_size,
                              hipStream_t stream)
{
    const float* x  = (const float*)d_in[0];
    const float* w1 = (const float*)d_in[1];
    const float* b1 = (const float*)d_in[2];
    const float* C  = (const float*)d_in[3];
    const float* w2 = (const float*)d_in[4];
    const float* b2 = (const float*)d_in[5];
    float* out = (float*)d_out;
    float* ws  = (float*)d_ws;

    // ws layout (floats) — peak 12.13 MiB (proven budget):
    //   s       [0,       2M)          phases 1-2 (f32 [p][k])
    //   v       [2M,      3M)          phases 2-3
    //   w1t_h   [2M,      2M+16384)    phases 0-1 (dead-v; 32768 shorts)
    //   w1t_l   [2M+16384,2M+32768)    phases 0-1  << FIX: was +8192 ->
    //                                  w1t_l[k][d] aliased w1t_h[k+32][d]
    //   ap      [3M,      3M+32768)    phases 1-3
    //   ssp     [3M+32768, +128)       phases 5-6
    //   vn16    [0,       0.5M)        phases 3-4 (bf16, over dead s)
    //   outpart [0.5M,    2.5M)        phases 4-5 (over dead s-top + v)
    float* s_buf   = ws;
    float* v_buf   = ws + 2097152;
    unsigned short* w1t_h = (unsigned short*)(ws + 2097152);
    unsigned short* w1t_l = (unsigned short*)(ws + 2097152 + 16384);
    float* ap      = ws + 3145728;
    float* ssp     = ws + 3145728 + 32768;
    unsigned short* vn16 = (unsigned short*)ws;
    float* outpart = ws + 524288;

    k_prep  <<<32,  256, 0, stream>>>(w1, w1t_h, w1t_l);
    k_assign<<<512, 256, 0, stream>>>(x, w1t_h, w1t_l, b1, s_buf, ap);
    k_vlad  <<<512, 256, 0, stream>>>(s_buf, x, v_buf);
    k_norm  <<<512, 256, 0, stream>>>(v_buf, ap, C, vn16);
    k_gemm2 <<<512, 256, 0, stream>>>(vn16, w2, outpart);
    k_reduce<<<128, 256, 0, stream>>>(outpart, b2, out, ssp);
    k_scale <<<128, 256, 0, stream>>>(ssp, out);
}

// Round 11
// 191.709 us; speedup vs baseline: 5.0986x; 1.4168x over previous
//
#include <hip/hip_runtime.h>
#include <math.h>

#define EPSF 1e-12f
// N=32, HW=1024, D=512, K=64, OUT=4096, KD=32768

typedef __attribute__((ext_vector_type(8))) short short8v;  // 8 bf16
typedef __attribute__((ext_vector_type(4))) float f32x4;

__device__ __forceinline__ unsigned short f2bf(float f) {   // RNE
    unsigned int u = __float_as_uint(f);
    return (unsigned short)((u + 0x7FFF + ((u >> 16) & 1)) >> 16);
}
__device__ __forceinline__ float bf2f(unsigned short h) {
    return __uint_as_float(((unsigned int)h) << 16);
}

// ---- kernel 0: w1 [512 d][64 k] f32 -> w1t hi/lo bf16 [64 k][512 d] -------
__global__ __launch_bounds__(256) void k_prep(
    const float* __restrict__ w1,
    unsigned short* __restrict__ w1t_h, unsigned short* __restrict__ w1t_l)
{
    const int i  = blockIdx.x * 256 + threadIdx.x;   // 0..8191
    const int k  = i >> 7;
    const int d0 = (i & 127) << 2;
    float vv[4];
#pragma unroll
    for (int j = 0; j < 4; ++j) vv[j] = w1[(size_t)(d0 + j) * 64 + k];
    ushort4 h, l;
    h.x = f2bf(vv[0]); l.x = f2bf(vv[0] - bf2f(h.x));
    h.y = f2bf(vv[1]); l.y = f2bf(vv[1] - bf2f(h.y));
    h.z = f2bf(vv[2]); l.z = f2bf(vv[2] - bf2f(h.z));
    h.w = f2bf(vv[3]); l.w = f2bf(vv[3] - bf2f(h.w));
    *(ushort4*)(w1t_h + (size_t)k * 512 + d0) = h;
    *(ushort4*)(w1t_l + (size_t)k * 512 + d0) = l;
}

// ---- kernel 1: logits = x @ W1 (split-bf16 MFMA, r10-proven core) ---------
// + r8 in-register softmax epilogue (retrial: its r8 conviction was the
// w1t allocation overlap, fixed in r10). D: row=4*l4+r -> px, col=l16 -> k.
// Softmax over k: in-lane over nf + shfl_xor {1,2,4,8} over l16.
// Outputs st hi/lo bf16 TRANSPOSED [n*64+k][1024 p] + ap column sums.
__global__ __launch_bounds__(256) void k_assign(
    const float* __restrict__ x,
    const unsigned short* __restrict__ w1t_h,
    const unsigned short* __restrict__ w1t_l,
    const float* __restrict__ b1,
    unsigned short* __restrict__ st_h, unsigned short* __restrict__ st_l,
    float* __restrict__ ap)
{
    const int tid  = threadIdx.x;
    const int lane = tid & 63;
    const int wv   = __builtin_amdgcn_readfirstlane(tid >> 6);  // 0..3
    const int l4   = lane >> 4;
    const int l16  = lane & 15;
    const int pix0 = blockIdx.x * 64;
    const int n_img  = blockIdx.x >> 4;
    const int p_base = (blockIdx.x & 15) * 64;

    __shared__ unsigned short Xh[64][72];   // +8 pad: conflict-free b128
    __shared__ unsigned short Xl[64][72];
    __shared__ float apred[4][64];

    f32x4 acc[4];
#pragma unroll
    for (int nf = 0; nf < 4; ++nf) acc[nf] = (f32x4){0.f, 0.f, 0.f, 0.f};

    float4 xr[4];
#pragma unroll
    for (int t = 0; t < 4; ++t) {            // prologue: chunk 0 -> regs
        int idx = tid + t * 256, p = idx >> 4, d4 = (idx & 15) << 2;
        xr[t] = *(const float4*)&x[(size_t)(pix0 + p) * 512 + d4];
    }

    for (int c = 0; c < 8; ++c) {
        __syncthreads();                     // prev chunk's LDS reads done
#pragma unroll
        for (int t = 0; t < 4; ++t) {        // cvt + write LDS (split pair)
            int idx = tid + t * 256, p = idx >> 4, d4 = (idx & 15) << 2;
            float4 v = xr[t];
            ushort4 h4, l4v;
            h4.x = f2bf(v.x); l4v.x = f2bf(v.x - bf2f(h4.x));
            h4.y = f2bf(v.y); l4v.y = f2bf(v.y - bf2f(h4.y));
            h4.z = f2bf(v.z); l4v.z = f2bf(v.z - bf2f(h4.z));
            h4.w = f2bf(v.w); l4v.w = f2bf(v.w - bf2f(h4.w));
            *(ushort4*)&Xh[p][d4] = h4;
            *(ushort4*)&Xl[p][d4] = l4v;
        }
        if (c + 1 < 8) {                     // prefetch next chunk
#pragma unroll
            for (int t = 0; t < 4; ++t) {
                int idx = tid + t * 256, p = idx >> 4, d4 = (idx & 15) << 2;
                xr[t] = *(const float4*)&x[(size_t)(pix0 + p) * 512 +
                                           (c + 1) * 64 + d4];
            }
        }
        __syncthreads();
#pragma unroll
        for (int ks = 0; ks < 2; ++ks) {     // 2 k-steps of 32 d
            short8v ah = *(const short8v*)&Xh[wv * 16 + l16][ks * 32 + l4 * 8];
            short8v al = *(const short8v*)&Xl[wv * 16 + l16][ks * 32 + l4 * 8];
#pragma unroll
            for (int nf = 0; nf < 4; ++nf) {
                const size_t wo = (size_t)(nf * 16 + l16) * 512 +
                                  c * 64 + ks * 32 + l4 * 8;
                short8v bh = *(const short8v*)(w1t_h + wo);
                short8v bl = *(const short8v*)(w1t_l + wo);
                acc[nf] = __builtin_amdgcn_mfma_f32_16x16x32_bf16(ah, bh, acc[nf], 0, 0, 0);
                acc[nf] = __builtin_amdgcn_mfma_f32_16x16x32_bf16(ah, bl, acc[nf], 0, 0, 0);
                acc[nf] = __builtin_amdgcn_mfma_f32_16x16x32_bf16(al, bh, acc[nf], 0, 0, 0);
            }
        }
    }

    // epilogue: +b1, softmax over k (px = wv*16 + 4*l4 + r, k = nf*16 + l16)
    float lg[4][4];                          // [nf][r]
#pragma unroll
    for (int nf = 0; nf < 4; ++nf) {
        const float bb = b1[nf * 16 + l16];
#pragma unroll
        for (int r = 0; r < 4; ++r) lg[nf][r] = acc[nf][r] + bb;
    }
    float mx[4], sm[4];
#pragma unroll
    for (int r = 0; r < 4; ++r)
        mx[r] = fmaxf(fmaxf(lg[0][r], lg[1][r]), fmaxf(lg[2][r], lg[3][r]));
#pragma unroll
    for (int m = 1; m <= 8; m <<= 1)
#pragma unroll
        for (int r = 0; r < 4; ++r) mx[r] = fmaxf(mx[r], __shfl_xor(mx[r], m, 64));
#pragma unroll
    for (int r = 0; r < 4; ++r) sm[r] = 0.f;
#pragma unroll
    for (int nf = 0; nf < 4; ++nf)
#pragma unroll
        for (int r = 0; r < 4; ++r) { lg[nf][r] = __expf(lg[nf][r] - mx[r]); sm[r] += lg[nf][r]; }
#pragma unroll
    for (int m = 1; m <= 8; m <<= 1)
#pragma unroll
        for (int r = 0; r < 4; ++r) sm[r] += __shfl_xor(sm[r], m, 64);

    // s values -> st (transposed, split) + ap partials
#pragma unroll
    for (int nf = 0; nf < 4; ++nf) {
        float sv[4];
        ushort4 hh, ll;
#pragma unroll
        for (int r = 0; r < 4; ++r) sv[r] = lg[nf][r] * (1.0f / sm[r]);
        hh.x = f2bf(sv[0]); ll.x = f2bf(sv[0] - bf2f(hh.x));
        hh.y = f2bf(sv[1]); ll.y = f2bf(sv[1] - bf2f(hh.y));
        hh.z = f2bf(sv[2]); ll.z = f2bf(sv[2] - bf2f(hh.z));
        hh.w = f2bf(sv[3]); ll.w = f2bf(sv[3] - bf2f(hh.w));
        const size_t so = (size_t)(n_img * 64 + nf * 16 + l16) * 1024 +
                          p_base + wv * 16 + l4 * 4;
        *(ushort4*)(st_h + so) = hh;
        *(ushort4*)(st_l + so) = ll;
        float tsum = sv[0] + sv[1] + sv[2] + sv[3];
        tsum += __shfl_xor(tsum, 16, 64);
        tsum += __shfl_xor(tsum, 32, 64);
        if (l4 == 0) apred[wv][nf * 16 + l16] = tsum;
    }
    __syncthreads();
    if (tid < 64)
        ap[(size_t)blockIdx.x * 64 + tid] =
            (apred[0][tid] + apred[1][tid]) + (apred[2][tid] + apred[3][tid]);
}

// ---- kernel 2: v[k][d] = sum_p st[k][p]*x[p][d]  (split-bf16 MFMA) --------
// grid 512 = n(32) x dchunk(16 of 32 d); 128 thr (2 waves). Wave w: 16 d
// (n-frag), 4 m-frags (64 k). A = st rows (global, L2-hot, contiguous p);
// B = x columns from LDS f32 tile (global_load_lds staged, linear), cvt'd
// to bf16 pair in-reg. 3-term split. x read ONCE (64 MB).
__global__ __launch_bounds__(128) void k_vlad(
    const unsigned short* __restrict__ st_h,
    const unsigned short* __restrict__ st_l,
    const float* __restrict__ x, float* __restrict__ v)
{
    __shared__ float X2[2][32][32];          // 8 KB double-buffered

    const int tid  = threadIdx.x;
    const int lane = tid & 63;
    const int w    = __builtin_amdgcn_readfirstlane(tid >> 6);  // 0/1
    const int l4   = lane >> 4;
    const int l16  = lane & 15;
    const int n    = blockIdx.x >> 4;
    const int dc   = blockIdx.x & 15;
    const int dbase = dc * 32;

    f32x4 acc[4];                            // [mf]
#pragma unroll
    for (int mf = 0; mf < 4; ++mf) acc[mf] = (f32x4){0.f, 0.f, 0.f, 0.f};

    // stage x[t*32..+32 p][dbase..+32 d] f32: 4 KB = 4 x 1KB instrs (2/wave)
#define VSTAGE(T_, B_)                                                        \
    do {                                                                      \
        _Pragma("unroll")                                                     \
        for (int i_ = 0; i_ < 2; ++i_) {                                      \
            const int jj_ = w * 2 + i_;                                       \
            __builtin_amdgcn_global_load_lds(                                 \
                (const __attribute__((address_space(1))) void*)               \
                    (x + (size_t)(n * 1024 + (T_) * 32 + jj_ * 8 +            \
                                  (lane >> 3)) * 512 + dbase + (lane & 7) * 4), \
                (__attribute__((address_space(3))) void*)&X2[B_][jj_ * 8][0], \
                16, 0, 0);                                                    \
        }                                                                     \
    } while (0)

    VSTAGE(0, 0);
    __syncthreads();

    int buf = 0;
    for (int t = 0; t < 32; ++t) {
        if (t + 1 < 32) VSTAGE(t + 1, buf ^ 1);

        // A-frags (st, k-dim = p contiguous)
        const size_t sbase = (size_t)(n * 64) * 1024 + t * 32 + l4 * 8;
        short8v ah[4], al[4];
#pragma unroll
        for (int mf = 0; mf < 4; ++mf) {
            ah[mf] = *(const short8v*)(st_h + sbase + (size_t)(mf * 16 + l16) * 1024);
            al[mf] = *(const short8v*)(st_l + sbase + (size_t)(mf * 16 + l16) * 1024);
        }
        // B-frag: column d = dbase + w*16 + l16, p = l4*8 + j (4-way conflict)
        short8v bh, bl;
#pragma unroll
        for (int j = 0; j < 8; ++j) {
            float bx = X2[buf][l4 * 8 + j][w * 16 + l16];
            unsigned short hb = f2bf(bx);
            bh[j] = (short)hb;
            bl[j] = (short)f2bf(bx - bf2f(hb));
        }
#pragma unroll
        for (int mf = 0; mf < 4; ++mf) {
            acc[mf] = __builtin_amdgcn_mfma_f32_16x16x32_bf16(ah[mf], bh, acc[mf], 0, 0, 0);
            acc[mf] = __builtin_amdgcn_mfma_f32_16x16x32_bf16(ah[mf], bl, acc[mf], 0, 0, 0);
            acc[mf] = __builtin_amdgcn_mfma_f32_16x16x32_bf16(al[mf], bh, acc[mf], 0, 0, 0);
        }
        __syncthreads();
        buf ^= 1;
    }
#undef VSTAGE

    // D: row = 4*l4+r -> k = mf*16+4*l4+r; col = l16 -> d = dbase+w*16+l16
#pragma unroll
    for (int mf = 0; mf < 4; ++mf)
#pragma unroll
        for (int r = 0; r < 4; ++r)
            v[(size_t)(n * 64 + mf * 16 + 4 * l4 + r) * 512 +
              dbase + w * 16 + l16] = acc[mf][r];
}

// ---- kernel 3: vn16 = bf16( intra-L2-norm(v + a*C) * 1/8 )  (r7-proven) ---
__global__ __launch_bounds__(256) void k_norm(
    const float* __restrict__ v, const float* __restrict__ ap,
    const float* __restrict__ C, unsigned short* __restrict__ vn16)
{
    const int lane = threadIdx.x & 63;
    const int w    = threadIdx.x >> 6;
    const int row  = blockIdx.x * 4 + w;   // n*64 + k
    const int n    = row >> 6;
    const int k    = row & 63;

    float a_nk = 0.f;
#pragma unroll
    for (int t = 0; t < 16; ++t)
        a_nk += ap[((size_t)(n * 16 + t)) * 64 + k];

    const float* vr = v + (size_t)row * 512;
    float vv[8];
    float ss = 0.f;
#pragma unroll
    for (int j = 0; j < 8; ++j) {
        int d = j * 64 + lane;
        float t = vr[d] + a_nk * C[(size_t)d * 64 + k];
        vv[j] = t;
        ss = fmaf(t, t, ss);
    }
#pragma unroll
    for (int off = 32; off > 0; off >>= 1) ss += __shfl_xor(ss, off, 64);
    const float scale = rsqrtf(fmaxf(ss, EPSF)) * 0.125f;
    unsigned short* vo = vn16 + (size_t)row * 512;
#pragma unroll
    for (int j = 0; j < 8; ++j) vo[j * 64 + lane] = f2bf(vv[j] * scale);
}

// ---- kernel 4: outpart[kc] = vn @ W2 slice (bf16 MFMA)  (r7-proven) -------
__global__ __launch_bounds__(256, 2) void k_gemm2(
    const unsigned short* __restrict__ vn16, const float* __restrict__ w2,
    float* __restrict__ outpart)
{
    __shared__ float Bs[2][32][128];   // 32 KB double-buffered w2 tile

    const int tid  = threadIdx.x;
    const int lane = tid & 63;
    const int wv   = __builtin_amdgcn_readfirstlane(tid >> 6);  // 0..3
    const int kc   = blockIdx.x >> 5;
    const int cb   = blockIdx.x & 31;
    const int rowbase = kc * 2048;
    const int colbase = cb * 128;
    const int l4   = lane >> 4;
    const int l16  = lane & 15;

    f32x4 acc[2][2];
#pragma unroll
    for (int i = 0; i < 2; ++i)
#pragma unroll
        for (int j = 0; j < 2; ++j)
            acc[i][j] = (f32x4){0.f, 0.f, 0.f, 0.f};

#define STAGE(T_, B_)                                                         \
    do {                                                                      \
        _Pragma("unroll")                                                     \
        for (int i_ = 0; i_ < 4; ++i_) {                                      \
            const int r_ = (wv * 4 + i_) * 2 + (lane >> 5);                   \
            __builtin_amdgcn_global_load_lds(                                 \
                (const __attribute__((address_space(1))) void*)               \
                    (w2 + (size_t)(rowbase + (T_) * 32 + r_) * 4096 +         \
                     colbase + (lane & 31) * 4),                              \
                (__attribute__((address_space(3))) void*)                     \
                    &Bs[B_][(wv * 4 + i_) * 2][0],                            \
                16, 0, 0);                                                    \
        }                                                                     \
    } while (0)

    STAGE(0, 0);
    __syncthreads();

    int buf = 0;
    for (int t = 0; t < 64; ++t) {
        if (t + 1 < 64) STAGE(t + 1, buf ^ 1);

        const unsigned short* va = vn16 + (size_t)(rowbase + t * 32 + l4 * 8);
        short8v a0 = *(const short8v*)(va + (size_t)l16 * 32768);
        short8v a1 = *(const short8v*)(va + (size_t)(16 + l16) * 32768);

#pragma unroll
        for (int nf = 0; nf < 2; ++nf) {
            const int cl = wv * 32 + nf * 16 + l16;
            short8v bfr;
#pragma unroll
            for (int j = 0; j < 8; ++j)
                bfr[j] = (short)f2bf(Bs[buf][l4 * 8 + j][cl]);
            acc[0][nf] = __builtin_amdgcn_mfma_f32_16x16x32_bf16(
                a0, bfr, acc[0][nf], 0, 0, 0);
            acc[1][nf] = __builtin_amdgcn_mfma_f32_16x16x32_bf16(
                a1, bfr, acc[1][nf], 0, 0, 0);
        }
        __syncthreads();
        buf ^= 1;
    }
#undef STAGE

#pragma unroll
    for (int mf = 0; mf < 2; ++mf)
#pragma unroll
        for (int nf = 0; nf < 2; ++nf)
#pragma unroll
            for (int r = 0; r < 4; ++r) {
                const int m  = mf * 16 + l4 * 4 + r;
                const int cl = colbase + wv * 32 + nf * 16 + l16;
                outpart[(size_t)kc * 131072 + (size_t)m * 4096 + cl] =
                    acc[mf][nf][r];
            }
}

// ---- kernel 5: reduce 16 partials + bias, per-block sumsq -----------------
__global__ __launch_bounds__(256) void k_reduce(
    const float* __restrict__ outpart, const float* __restrict__ b2,
    float* __restrict__ out, float* __restrict__ ssp)
{
    const int i = (blockIdx.x * 256 + threadIdx.x) * 4;
    float4 o = make_float4(0.f, 0.f, 0.f, 0.f);
#pragma unroll
    for (int kc = 0; kc < 16; ++kc) {
        float4 t = *(const float4*)&outpart[(size_t)kc * 131072 + i];
        o.x += t.x; o.y += t.y; o.z += t.z; o.w += t.w;
    }
    float4 bb = *(const float4*)&b2[i & 4095];
    o.x += bb.x; o.y += bb.y; o.z += bb.z; o.w += bb.w;
    *(float4*)&out[i] = o;

    float ss = o.x * o.x + o.y * o.y + o.z * o.z + o.w * o.w;
#pragma unroll
    for (int off = 32; off > 0; off >>= 1) ss += __shfl_xor(ss, off, 64);
    __shared__ float lred[4];
    if ((threadIdx.x & 63) == 0) lred[threadIdx.x >> 6] = ss;
    __syncthreads();
    if (threadIdx.x == 0)
        ssp[blockIdx.x] = lred[0] + lred[1] + lred[2] + lred[3];
}

// ---- kernel 6: global L2 scale --------------------------------------------
__global__ __launch_bounds__(256) void k_scale(
    const float* __restrict__ ssp, float* __restrict__ out)
{
    float ss = 0.f;
#pragma unroll
    for (int t = 0; t < 128; ++t) ss += ssp[t];
    const float sc = rsqrtf(fmaxf(ss, EPSF));
    const int i = (blockIdx.x * 256 + threadIdx.x) * 4;
    float4 o = *(float4*)&out[i];
    o.x *= sc; o.y *= sc; o.z *= sc; o.w *= sc;
    *(float4*)&out[i] = o;
}

extern "C" void kernel_launch(void* const* d_in, const int* in_sizes, int n_in,
                              void* d_out, int out_size, void* d_ws, size_t ws_size,
                              hipStream_t stream)
{
    const float* x  = (const float*)d_in[0];
    const float* w1 = (const float*)d_in[1];
    const float* b1 = (const float*)d_in[2];
    const float* C  = (const float*)d_in[3];
    const float* w2 = (const float*)d_in[4];
    const float* b2 = (const float*)d_in[5];
    float* out = (float*)d_out;
    float* ws  = (float*)d_ws;

    // ws layout (floats) — peak 12.13 MiB (proven budget):
    //   st_h    [0,       1M)          phases 1-2 (bf16 hi, 4 MB)
    //   st_l    [1M,      2M)          phases 1-2 (bf16 lo)
    //   v       [2M,      3M)          phases 2-3
    //   w1t_h   [2M,      2M+16384)    phases 0-1 (dead-v; 32768 shorts)
    //   w1t_l   [2M+16384,2M+32768)    phases 0-1 (r10-fixed offset)
    //   ap      [3M,      3M+32768)    phases 1-3
    //   ssp     [3M+32768, +128)       phases 5-6
    //   vn16    [0,       0.5M)        phases 3-4 (bf16, over dead st_h)
    //   outpart [0.5M,    2.5M)        phases 4-5 (over dead st/v)
    unsigned short* st_h = (unsigned short*)ws;
    unsigned short* st_l = (unsigned short*)(ws + 1048576);
    float* v_buf   = ws + 2097152;
    unsigned short* w1t_h = (unsigned short*)(ws + 2097152);
    unsigned short* w1t_l = (unsigned short*)(ws + 2097152 + 16384);
    float* ap      = ws + 3145728;
    float* ssp     = ws + 3145728 + 32768;
    unsigned short* vn16 = (unsigned short*)ws;
    float* outpart = ws + 524288;

    k_prep  <<<32,  256, 0, stream>>>(w1, w1t_h, w1t_l);
    k_assign<<<512, 256, 0, stream>>>(x, w1t_h, w1t_l, b1, st_h, st_l, ap);
    k_vlad  <<<512, 128, 0, stream>>>(st_h, st_l, x, v_buf);
    k_norm  <<<512, 256, 0, stream>>>(v_buf, ap, C, vn16);
    k_gemm2 <<<512, 256, 0, stream>>>(vn16, w2, outpart);
    k_reduce<<<128, 256, 0, stream>>>(outpart, b2, out, ssp);
    k_scale <<<128, 256, 0, stream>>>(ssp, out);
}